// Round 1
// baseline (1423.668 us; speedup 1.0000x reference)
//
#include <hip/hip_runtime.h>
#include <math.h>

#define NHEAD 16
#define HD 64
#define DMODEL 1024
#define SEQ 1024
#define BATCH 8
#define ROWS (BATCH * SEQ)   // 8192

// ---------------------------------------------------------------------------
// GEMM: C[M,N] = A[M,K] @ B[N,K]^T   (all row-major f32)
// 64x64 tile, BK=32, 256 threads, 4x4 per thread. Pad-33 LDS (banks ~2-way).
// ---------------------------------------------------------------------------
__global__ __launch_bounds__(256) void gemm_abt(const float* __restrict__ A,
                                                const float* __restrict__ Bw,
                                                float* __restrict__ C,
                                                int M, int N, int K) {
    __shared__ float sA[64][33];
    __shared__ float sB[64][33];
    const int tid = threadIdx.x;
    const int tx = tid & 15, ty = tid >> 4;
    const int m0 = blockIdx.y * 64;
    const int n0 = blockIdx.x * 64;

    float acc[4][4] = {};

    for (int k0 = 0; k0 < K; k0 += 32) {
#pragma unroll
        for (int p = 0; p < 2; ++p) {
            int i  = tid + p * 256;          // 0..511
            int r  = i >> 3;                 // 0..63
            int c4 = (i & 7) << 2;           // 0,4,..,28
            float4 a = *(const float4*)(A + (size_t)(m0 + r) * K + k0 + c4);
            sA[r][c4 + 0] = a.x; sA[r][c4 + 1] = a.y;
            sA[r][c4 + 2] = a.z; sA[r][c4 + 3] = a.w;
            float4 b = *(const float4*)(Bw + (size_t)(n0 + r) * K + k0 + c4);
            sB[r][c4 + 0] = b.x; sB[r][c4 + 1] = b.y;
            sB[r][c4 + 2] = b.z; sB[r][c4 + 3] = b.w;
        }
        __syncthreads();

#pragma unroll
        for (int kk = 0; kk < 32; ++kk) {
            float a[4], b[4];
#pragma unroll
            for (int i = 0; i < 4; ++i) a[i] = sA[ty * 4 + i][kk];
#pragma unroll
            for (int j = 0; j < 4; ++j) b[j] = sB[tx * 4 + j][kk];
#pragma unroll
            for (int i = 0; i < 4; ++i)
#pragma unroll
                for (int j = 0; j < 4; ++j)
                    acc[i][j] = fmaf(a[i], b[j], acc[i][j]);
        }
        __syncthreads();
    }

#pragma unroll
    for (int i = 0; i < 4; ++i)
#pragma unroll
        for (int j = 0; j < 4; ++j)
            C[(size_t)(m0 + ty * 4 + i) * N + n0 + tx * 4 + j] = acc[i][j];
}

// ---------------------------------------------------------------------------
// Fused per-head QKV projection. Block = (head h, 64-row tile).
// q[b,s,h,o] = sum_d xp[b,s,h,d] * Wq[h,o,d]   (q scaled by 1/sqrt(64))
// ---------------------------------------------------------------------------
__global__ __launch_bounds__(256) void qkv_kernel(const float* __restrict__ xp,
                                                  const float* __restrict__ Wq,
                                                  const float* __restrict__ Wk,
                                                  const float* __restrict__ Wv,
                                                  float* __restrict__ qb,
                                                  float* __restrict__ kb,
                                                  float* __restrict__ vb) {
    __shared__ float sX[64][65];
    __shared__ float sW[3][64][65];
    const int tid = threadIdx.x;
    const int tx = tid & 15, ty = tid >> 4;
    const int h  = blockIdx.x;           // 0..15
    const int r0 = blockIdx.y * 64;      // row tile

    const float* Ws0 = Wq + h * 4096;
    const float* Ws1 = Wk + h * 4096;
    const float* Ws2 = Wv + h * 4096;
#pragma unroll
    for (int p = 0; p < 4; ++p) {
        int i  = tid + p * 256;          // 0..1023
        int o  = i >> 4;
        int d4 = (i & 15) << 2;
        float4 t0 = *(const float4*)(Ws0 + o * 64 + d4);
        sW[0][o][d4 + 0] = t0.x; sW[0][o][d4 + 1] = t0.y;
        sW[0][o][d4 + 2] = t0.z; sW[0][o][d4 + 3] = t0.w;
        float4 t1 = *(const float4*)(Ws1 + o * 64 + d4);
        sW[1][o][d4 + 0] = t1.x; sW[1][o][d4 + 1] = t1.y;
        sW[1][o][d4 + 2] = t1.z; sW[1][o][d4 + 3] = t1.w;
        float4 t2 = *(const float4*)(Ws2 + o * 64 + d4);
        sW[2][o][d4 + 0] = t2.x; sW[2][o][d4 + 1] = t2.y;
        sW[2][o][d4 + 2] = t2.z; sW[2][o][d4 + 3] = t2.w;
    }
#pragma unroll
    for (int p = 0; p < 4; ++p) {
        int i  = tid + p * 256;
        int r  = i >> 4;
        int c4 = (i & 15) << 2;
        float4 t = *(const float4*)(xp + (size_t)(r0 + r) * DMODEL + h * 64 + c4);
        sX[r][c4 + 0] = t.x; sX[r][c4 + 1] = t.y;
        sX[r][c4 + 2] = t.z; sX[r][c4 + 3] = t.w;
    }
    __syncthreads();

    float aq[4][4] = {}, ak[4][4] = {}, av[4][4] = {};
#pragma unroll 4
    for (int d = 0; d < 64; ++d) {
        float x[4], wq[4], wk[4], wv[4];
#pragma unroll
        for (int i = 0; i < 4; ++i) x[i] = sX[ty * 4 + i][d];
#pragma unroll
        for (int j = 0; j < 4; ++j) {
            wq[j] = sW[0][tx * 4 + j][d];
            wk[j] = sW[1][tx * 4 + j][d];
            wv[j] = sW[2][tx * 4 + j][d];
        }
#pragma unroll
        for (int i = 0; i < 4; ++i)
#pragma unroll
            for (int j = 0; j < 4; ++j) {
                aq[i][j] = fmaf(x[i], wq[j], aq[i][j]);
                ak[i][j] = fmaf(x[i], wk[j], ak[i][j]);
                av[i][j] = fmaf(x[i], wv[j], av[i][j]);
            }
    }

#pragma unroll
    for (int i = 0; i < 4; ++i)
#pragma unroll
        for (int j = 0; j < 4; ++j) {
            size_t idx = (size_t)(r0 + ty * 4 + i) * DMODEL + h * 64 + tx * 4 + j;
            qb[idx] = aq[i][j] * 0.125f;   // fold 1/sqrt(64) into q
            kb[idx] = ak[i][j];
            vb[idx] = av[i][j];
        }
}

// ---------------------------------------------------------------------------
// Flash-style attention. Block = (64-row Q tile, b*16+h). 256 threads.
// Online softmax; row reductions via shfl_xor within 16-lane tx groups.
// ---------------------------------------------------------------------------
__global__ __launch_bounds__(256) void attn_kernel(const float* __restrict__ qb,
                                                   const float* __restrict__ kb,
                                                   const float* __restrict__ vb,
                                                   float* __restrict__ ob) {
    __shared__ float sQ[64][65];
    __shared__ float sK[64][65];
    __shared__ float sV[64][65];
    __shared__ float sP[64][65];
    const int tid = threadIdx.x;
    const int tx = tid & 15, ty = tid >> 4;
    const int bh = blockIdx.y;           // b*16+h
    const int b  = bh >> 4, h = bh & 15;
    const int s0 = blockIdx.x * 64;
    const size_t base = (size_t)b * SEQ * DMODEL + h * 64;

#pragma unroll
    for (int p = 0; p < 4; ++p) {
        int i  = tid + p * 256;
        int r  = i >> 4;
        int c4 = (i & 15) << 2;
        float4 t = *(const float4*)(qb + base + (size_t)(s0 + r) * DMODEL + c4);
        sQ[r][c4 + 0] = t.x; sQ[r][c4 + 1] = t.y;
        sQ[r][c4 + 2] = t.z; sQ[r][c4 + 3] = t.w;
    }

    float m[4], l[4], o[4][4] = {};
#pragma unroll
    for (int i = 0; i < 4; ++i) { m[i] = -1e30f; l[i] = 0.f; }

    for (int kt = 0; kt < SEQ / 64; ++kt) {
#pragma unroll
        for (int p = 0; p < 4; ++p) {
            int i  = tid + p * 256;
            int r  = i >> 4;
            int c4 = (i & 15) << 2;
            float4 tk = *(const float4*)(kb + base + (size_t)(kt * 64 + r) * DMODEL + c4);
            sK[r][c4 + 0] = tk.x; sK[r][c4 + 1] = tk.y;
            sK[r][c4 + 2] = tk.z; sK[r][c4 + 3] = tk.w;
            float4 tv = *(const float4*)(vb + base + (size_t)(kt * 64 + r) * DMODEL + c4);
            sV[r][c4 + 0] = tv.x; sV[r][c4 + 1] = tv.y;
            sV[r][c4 + 2] = tv.z; sV[r][c4 + 3] = tv.w;
        }
        __syncthreads();   // also covers the one-time sQ writes on first iter

        // S = Q @ K^T (q pre-scaled)
        float sv[4][4] = {};
#pragma unroll 4
        for (int d = 0; d < 64; ++d) {
            float qv[4], kv[4];
#pragma unroll
            for (int i = 0; i < 4; ++i) qv[i] = sQ[ty * 4 + i][d];
#pragma unroll
            for (int j = 0; j < 4; ++j) kv[j] = sK[tx * 4 + j][d];
#pragma unroll
            for (int i = 0; i < 4; ++i)
#pragma unroll
                for (int j = 0; j < 4; ++j)
                    sv[i][j] = fmaf(qv[i], kv[j], sv[i][j]);
        }

        // online softmax update
        float p_[4][4];
#pragma unroll
        for (int i = 0; i < 4; ++i) {
            float rmax = fmaxf(fmaxf(sv[i][0], sv[i][1]), fmaxf(sv[i][2], sv[i][3]));
#pragma unroll
            for (int off = 1; off < 16; off <<= 1)
                rmax = fmaxf(rmax, __shfl_xor(rmax, off, 64));
            float mn = fmaxf(m[i], rmax);
            float alpha = __expf(m[i] - mn);
            m[i] = mn;
            float rs = 0.f;
#pragma unroll
            for (int j = 0; j < 4; ++j) {
                p_[i][j] = __expf(sv[i][j] - mn);
                rs += p_[i][j];
            }
#pragma unroll
            for (int off = 1; off < 16; off <<= 1)
                rs += __shfl_xor(rs, off, 64);
            l[i] = l[i] * alpha + rs;
#pragma unroll
            for (int j = 0; j < 4; ++j) o[i][j] *= alpha;
        }

#pragma unroll
        for (int i = 0; i < 4; ++i)
#pragma unroll
            for (int j = 0; j < 4; ++j)
                sP[ty * 4 + i][tx * 4 + j] = p_[i][j];
        __syncthreads();

        // O += P @ V
#pragma unroll 4
        for (int j = 0; j < 64; ++j) {
            float pv[4], vv[4];
#pragma unroll
            for (int i = 0; i < 4; ++i) pv[i] = sP[ty * 4 + i][j];
#pragma unroll
            for (int c = 0; c < 4; ++c) vv[c] = sV[j][tx * 4 + c];
#pragma unroll
            for (int i = 0; i < 4; ++i)
#pragma unroll
                for (int c = 0; c < 4; ++c)
                    o[i][c] = fmaf(pv[i], vv[c], o[i][c]);
        }
        __syncthreads();
    }

#pragma unroll
    for (int i = 0; i < 4; ++i) {
        float inv = 1.f / l[i];
#pragma unroll
        for (int j = 0; j < 4; ++j)
            ob[base + (size_t)(s0 + ty * 4 + i) * DMODEL + tx * 4 + j] = o[i][j] * inv;
    }
}

// ---------------------------------------------------------------------------
extern "C" void kernel_launch(void* const* d_in, const int* in_sizes, int n_in,
                              void* d_out, int out_size, void* d_ws, size_t ws_size,
                              hipStream_t stream) {
    const float* x       = (const float*)d_in[0];
    const float* W_split = (const float*)d_in[1];
    const float* W_out   = (const float*)d_in[2];
    const float* Wq      = (const float*)d_in[3];
    const float* Wk      = (const float*)d_in[4];
    const float* Wv      = (const float*)d_in[5];
    float* out = (float*)d_out;

    float* xp = (float*)d_ws;                      // 8192x1024
    float* qb = xp + (size_t)ROWS * DMODEL;
    float* kb = qb + (size_t)ROWS * DMODEL;
    float* vb = kb + (size_t)ROWS * DMODEL;
    float* ob = xp;                                // reuse xp after qkv

    dim3 blk(256);

    // 1) xp = x @ W_split^T
    gemm_abt<<<dim3(DMODEL / 64, ROWS / 64), blk, 0, stream>>>(x, W_split, xp,
                                                               ROWS, DMODEL, DMODEL);
    // 2) q,k,v per-head projections (q pre-scaled by 0.125)
    qkv_kernel<<<dim3(NHEAD, ROWS / 64), blk, 0, stream>>>(xp, Wq, Wk, Wv, qb, kb, vb);
    // 3) flash attention -> ob (reuses xp)
    attn_kernel<<<dim3(SEQ / 64, BATCH * NHEAD), blk, 0, stream>>>(qb, kb, vb, ob);
    // 4) out = ob @ W_out^T
    gemm_abt<<<dim3(DMODEL / 64, ROWS / 64), blk, 0, stream>>>(ob, W_out, out,
                                                               ROWS, DMODEL, DMODEL);
}

// Round 2
// 825.566 us; speedup vs baseline: 1.7245x; 1.7245x over previous
//
#include <hip/hip_runtime.h>
#include <math.h>

#define NHEAD 16
#define HD 64
#define DMODEL 1024
#define SEQ 1024
#define BATCH 8
#define ROWS (BATCH * SEQ)   // 8192

typedef __attribute__((ext_vector_type(8))) short bf16x8;
typedef __attribute__((ext_vector_type(4))) float f32x4;
typedef __attribute__((ext_vector_type(4))) short short4v;

__device__ __forceinline__ unsigned short f2bf(float f) {
    unsigned u = __builtin_bit_cast(unsigned, f);
    u += 0x7FFF + ((u >> 16) & 1);          // RNE
    return (unsigned short)(u >> 16);
}

__device__ __forceinline__ void gload16(const void* g, void* l) {
    __builtin_amdgcn_global_load_lds(
        (const __attribute__((address_space(1))) unsigned int*)g,
        (__attribute__((address_space(3))) unsigned int*)l, 16, 0, 0);
}

// ---------------------------------------------------------------------------
// GEMM: C[M,N] = A[M,K] @ B[N,K]^T   (all row-major f32) — unchanged
// ---------------------------------------------------------------------------
__global__ __launch_bounds__(256) void gemm_abt(const float* __restrict__ A,
                                                const float* __restrict__ Bw,
                                                float* __restrict__ C,
                                                int M, int N, int K) {
    __shared__ float sA[64][33];
    __shared__ float sB[64][33];
    const int tid = threadIdx.x;
    const int tx = tid & 15, ty = tid >> 4;
    const int m0 = blockIdx.y * 64;
    const int n0 = blockIdx.x * 64;

    float acc[4][4] = {};

    for (int k0 = 0; k0 < K; k0 += 32) {
#pragma unroll
        for (int p = 0; p < 2; ++p) {
            int i  = tid + p * 256;
            int r  = i >> 3;
            int c4 = (i & 7) << 2;
            float4 a = *(const float4*)(A + (size_t)(m0 + r) * K + k0 + c4);
            sA[r][c4 + 0] = a.x; sA[r][c4 + 1] = a.y;
            sA[r][c4 + 2] = a.z; sA[r][c4 + 3] = a.w;
            float4 b = *(const float4*)(Bw + (size_t)(n0 + r) * K + k0 + c4);
            sB[r][c4 + 0] = b.x; sB[r][c4 + 1] = b.y;
            sB[r][c4 + 2] = b.z; sB[r][c4 + 3] = b.w;
        }
        __syncthreads();

#pragma unroll
        for (int kk = 0; kk < 32; ++kk) {
            float a[4], b[4];
#pragma unroll
            for (int i = 0; i < 4; ++i) a[i] = sA[ty * 4 + i][kk];
#pragma unroll
            for (int j = 0; j < 4; ++j) b[j] = sB[tx * 4 + j][kk];
#pragma unroll
            for (int i = 0; i < 4; ++i)
#pragma unroll
                for (int j = 0; j < 4; ++j)
                    acc[i][j] = fmaf(a[i], b[j], acc[i][j]);
        }
        __syncthreads();
    }

#pragma unroll
    for (int i = 0; i < 4; ++i)
#pragma unroll
        for (int j = 0; j < 4; ++j)
            C[(size_t)(m0 + ty * 4 + i) * N + n0 + tx * 4 + j] = acc[i][j];
}

// ---------------------------------------------------------------------------
// Fused per-head QKV projection -> bf16 outputs.
// qb/kb: [row][DMODEL] bf16 (q pre-scaled 0.125). vT: [b,h,d,s] bf16.
// ---------------------------------------------------------------------------
__global__ __launch_bounds__(256) void qkv_kernel(const float* __restrict__ xp,
                                                  const float* __restrict__ Wq,
                                                  const float* __restrict__ Wk,
                                                  const float* __restrict__ Wv,
                                                  unsigned short* __restrict__ qb,
                                                  unsigned short* __restrict__ kb,
                                                  unsigned short* __restrict__ vT) {
    __shared__ float sX[64][65];
    __shared__ float sW[3][64][65];
    const int tid = threadIdx.x;
    const int tx = tid & 15, ty = tid >> 4;
    const int h  = blockIdx.x;           // 0..15
    const int r0 = blockIdx.y * 64;      // global row tile

    const float* Ws0 = Wq + h * 4096;
    const float* Ws1 = Wk + h * 4096;
    const float* Ws2 = Wv + h * 4096;
#pragma unroll
    for (int p = 0; p < 4; ++p) {
        int i  = tid + p * 256;
        int o  = i >> 4;
        int d4 = (i & 15) << 2;
        float4 t0 = *(const float4*)(Ws0 + o * 64 + d4);
        sW[0][o][d4 + 0] = t0.x; sW[0][o][d4 + 1] = t0.y;
        sW[0][o][d4 + 2] = t0.z; sW[0][o][d4 + 3] = t0.w;
        float4 t1 = *(const float4*)(Ws1 + o * 64 + d4);
        sW[1][o][d4 + 0] = t1.x; sW[1][o][d4 + 1] = t1.y;
        sW[1][o][d4 + 2] = t1.z; sW[1][o][d4 + 3] = t1.w;
        float4 t2 = *(const float4*)(Ws2 + o * 64 + d4);
        sW[2][o][d4 + 0] = t2.x; sW[2][o][d4 + 1] = t2.y;
        sW[2][o][d4 + 2] = t2.z; sW[2][o][d4 + 3] = t2.w;
    }
#pragma unroll
    for (int p = 0; p < 4; ++p) {
        int i  = tid + p * 256;
        int r  = i >> 4;
        int c4 = (i & 15) << 2;
        float4 t = *(const float4*)(xp + (size_t)(r0 + r) * DMODEL + h * 64 + c4);
        sX[r][c4 + 0] = t.x; sX[r][c4 + 1] = t.y;
        sX[r][c4 + 2] = t.z; sX[r][c4 + 3] = t.w;
    }
    __syncthreads();

    float aq[4][4] = {}, ak[4][4] = {}, av[4][4] = {};
#pragma unroll 4
    for (int d = 0; d < 64; ++d) {
        float x[4], wq[4], wk[4], wv[4];
#pragma unroll
        for (int i = 0; i < 4; ++i) x[i] = sX[ty * 4 + i][d];
#pragma unroll
        for (int j = 0; j < 4; ++j) {
            wq[j] = sW[0][tx * 4 + j][d];
            wk[j] = sW[1][tx * 4 + j][d];
            wv[j] = sW[2][tx * 4 + j][d];
        }
#pragma unroll
        for (int i = 0; i < 4; ++i)
#pragma unroll
            for (int j = 0; j < 4; ++j) {
                aq[i][j] = fmaf(x[i], wq[j], aq[i][j]);
                ak[i][j] = fmaf(x[i], wk[j], ak[i][j]);
                av[i][j] = fmaf(x[i], wv[j], av[i][j]);
            }
    }

    const int b  = r0 >> 10;
    const int sl = r0 & 1023;
#pragma unroll
    for (int i = 0; i < 4; ++i) {
        size_t rowbase = (size_t)(r0 + ty * 4 + i) * DMODEL + h * 64 + tx * 4;
        short4v pq, pk;
#pragma unroll
        for (int j = 0; j < 4; ++j) {
            pq[j] = (short)f2bf(aq[i][j] * 0.125f);
            pk[j] = (short)f2bf(ak[i][j]);
        }
        *(short4v*)(qb + rowbase) = pq;
        *(short4v*)(kb + rowbase) = pk;
    }
#pragma unroll
    for (int j = 0; j < 4; ++j) {
        short4v pv;
#pragma unroll
        for (int i = 0; i < 4; ++i) pv[i] = (short)f2bf(av[i][j]);
        size_t idx = ((size_t)((b * 16 + h) * 64 + tx * 4 + j)) * SEQ + sl + ty * 4;
        *(short4v*)(vT + idx) = pv;
    }
}

// ---------------------------------------------------------------------------
// MFMA flash attention. 256 thr = 4 waves; wave w owns 16 q-rows.
// sK/sV: 64x128B XOR-swizzled (byte ^= (row&7)<<4), staged via global_load_lds
// with pre-swizzled source. sP: per-wave 16x128B, same swizzle.
// ---------------------------------------------------------------------------
__global__ __launch_bounds__(256) void attn_mfma(const unsigned short* __restrict__ qb,
                                                 const unsigned short* __restrict__ kb,
                                                 const unsigned short* __restrict__ vT,
                                                 float* __restrict__ ob) {
    __shared__ unsigned short sK[4096];  // 8 KB
    __shared__ unsigned short sV[4096];  // 8 KB (V^T tile: row=d, col=key)
    __shared__ unsigned short sP[4096];  // 4 waves x 16 rows x 128B

    const int tid  = threadIdx.x;
    const int w    = tid >> 6;
    const int lane = tid & 63;
    const int lr   = lane & 15;
    const int lg   = lane >> 4;          // 0..3
    const int bh   = blockIdx.y;
    const int b    = bh >> 4, h = bh & 15;
    const int s0   = blockIdx.x * 64;

    // Q fragments (rows s0+w*16+lr, k = k2*32 + lg*8 + e)
    const unsigned short* qrow = qb + ((size_t)(b * SEQ + s0 + w * 16 + lr) * DMODEL + h * 64);
    bf16x8 qf0 = *(const bf16x8*)(qrow + lg * 8);
    bf16x8 qf1 = *(const bf16x8*)(qrow + 32 + lg * 8);

    f32x4 o_acc[4] = {};
    float m_[4], l_[4];
#pragma unroll
    for (int r = 0; r < 4; ++r) { m_[r] = -1e30f; l_[r] = 0.f; }

    // staging geometry: per 1KB chunk, row = chunkrow8 + (lane>>3), off = (lane&7)*16
    const int srow = lane >> 3;                // 0..7  (== row & 7)
    const int ssw  = ((lane & 7) << 4) ^ (srow << 4);  // pre-swizzled byte-in-row

    for (int kt = 0; kt < SEQ / 64; ++kt) {
        __syncthreads();
#pragma unroll
        for (int c = 0; c < 2; ++c) {
            int chunk = w * 2 + c;               // 0..7
            int row   = chunk * 8 + srow;        // 0..63
            const char* gk = (const char*)kb +
                (((size_t)(b * SEQ + kt * 64 + row) * DMODEL + h * 64) * 2) + ssw;
            gload16(gk, (char*)sK + chunk * 1024);
            const char* gv = (const char*)vT +
                (((size_t)(bh * 64 + row) * SEQ + kt * 64) * 2) + ssw;
            gload16(gv, (char*)sV + chunk * 1024);
        }
        __syncthreads();

        // ---- S = Q K^T : 8 MFMA ----
        f32x4 s_acc[4] = {};
#pragma unroll
        for (int t = 0; t < 4; ++t) {
            int key = t * 16 + lr;
            int ksw = (key & 7) << 4;
            bf16x8 kf0 = *(const bf16x8*)((const char*)sK + key * 128 + ((lg * 16) ^ ksw));
            bf16x8 kf1 = *(const bf16x8*)((const char*)sK + key * 128 + ((64 + lg * 16) ^ ksw));
            s_acc[t] = __builtin_amdgcn_mfma_f32_16x16x32_bf16(qf0, kf0, s_acc[t], 0, 0, 0);
            s_acc[t] = __builtin_amdgcn_mfma_f32_16x16x32_bf16(qf1, kf1, s_acc[t], 0, 0, 0);
        }

        // ---- online softmax (rows q = lg*4+r, cols key = t*16+lr) ----
        float p[4][4], alpha[4];
#pragma unroll
        for (int r = 0; r < 4; ++r) {
            float mx = fmaxf(fmaxf(s_acc[0][r], s_acc[1][r]),
                             fmaxf(s_acc[2][r], s_acc[3][r]));
#pragma unroll
            for (int off = 1; off < 16; off <<= 1)
                mx = fmaxf(mx, __shfl_xor(mx, off, 64));
            float mn = fmaxf(m_[r], mx);
            alpha[r] = __expf(m_[r] - mn);
            m_[r] = mn;
            float rs = 0.f;
#pragma unroll
            for (int t = 0; t < 4; ++t) {
                p[t][r] = __expf(s_acc[t][r] - mn);
                rs += p[t][r];
            }
#pragma unroll
            for (int off = 1; off < 16; off <<= 1)
                rs += __shfl_xor(rs, off, 64);
            l_[r] = l_[r] * alpha[r] + rs;
        }
#pragma unroll
        for (int u = 0; u < 4; ++u)
#pragma unroll
            for (int r = 0; r < 4; ++r)
                o_acc[u][r] *= alpha[r];

        // ---- P -> LDS (bf16, per-wave region, swizzled) ----
#pragma unroll
        for (int r = 0; r < 4; ++r) {
            int q  = lg * 4 + r;
            int rb = w * 2048 + q * 128;
            int sw = (q & 7) << 4;
#pragma unroll
            for (int t = 0; t < 4; ++t) {
                int byteo = rb + (((t * 16 + lr) * 2) ^ sw);
                *(unsigned short*)((char*)sP + byteo) = f2bf(p[t][r]);
            }
        }

        // ---- O += P V : 8 MFMA ----
#pragma unroll
        for (int k2 = 0; k2 < 2; ++k2) {
            int psw = (lr & 7) << 4;
            bf16x8 pf = *(const bf16x8*)((const char*)sP + w * 2048 + lr * 128 +
                                         ((k2 * 64 + lg * 16) ^ psw));
#pragma unroll
            for (int u = 0; u < 4; ++u) {
                int d   = u * 16 + lr;
                int vsw = (d & 7) << 4;
                bf16x8 vf = *(const bf16x8*)((const char*)sV + d * 128 +
                                             ((k2 * 64 + lg * 16) ^ vsw));
                o_acc[u] = __builtin_amdgcn_mfma_f32_16x16x32_bf16(pf, vf, o_acc[u], 0, 0, 0);
            }
        }
    }

    // ---- store O (f32) ----
    float inv[4];
#pragma unroll
    for (int r = 0; r < 4; ++r) inv[r] = 1.f / l_[r];
#pragma unroll
    for (int u = 0; u < 4; ++u)
#pragma unroll
        for (int r = 0; r < 4; ++r)
            ob[(size_t)(b * SEQ + s0 + w * 16 + lg * 4 + r) * DMODEL + h * 64 + u * 16 + lr] =
                o_acc[u][r] * inv[r];
}

// ---------------------------------------------------------------------------
extern "C" void kernel_launch(void* const* d_in, const int* in_sizes, int n_in,
                              void* d_out, int out_size, void* d_ws, size_t ws_size,
                              hipStream_t stream) {
    const float* x       = (const float*)d_in[0];
    const float* W_split = (const float*)d_in[1];
    const float* W_out   = (const float*)d_in[2];
    const float* Wq      = (const float*)d_in[3];
    const float* Wk      = (const float*)d_in[4];
    const float* Wv      = (const float*)d_in[5];
    float* out = (float*)d_out;

    float* xp = (float*)d_ws;                                   // 32 MB f32
    unsigned short* qb = (unsigned short*)(xp + (size_t)ROWS * DMODEL);  // 16 MB bf16
    unsigned short* kb = qb + (size_t)ROWS * DMODEL;
    unsigned short* vT = kb + (size_t)ROWS * DMODEL;
    float* ob = xp;                                             // reuse xp after qkv

    dim3 blk(256);

    // 1) xp = x @ W_split^T   (f32)
    gemm_abt<<<dim3(DMODEL / 64, ROWS / 64), blk, 0, stream>>>(x, W_split, xp,
                                                               ROWS, DMODEL, DMODEL);
    // 2) q,k,v projections -> bf16 (q pre-scaled; v transposed to [b,h,d,s])
    qkv_kernel<<<dim3(NHEAD, ROWS / 64), blk, 0, stream>>>(xp, Wq, Wk, Wv, qb, kb, vT);
    // 3) MFMA flash attention -> ob f32 (reuses xp)
    attn_mfma<<<dim3(SEQ / 64, BATCH * NHEAD), blk, 0, stream>>>(qb, kb, vT, ob);
    // 4) out = ob @ W_out^T   (f32)
    gemm_abt<<<dim3(DMODEL / 64, ROWS / 64), blk, 0, stream>>>(ob, W_out, out,
                                                               ROWS, DMODEL, DMODEL);
}

// Round 3
// 235.286 us; speedup vs baseline: 6.0508x; 3.5088x over previous
//
#include <hip/hip_runtime.h>
#include <math.h>

#define NHEAD 16
#define HD 64
#define DMODEL 1024
#define SEQ 1024
#define BATCH 8
#define ROWS (BATCH * SEQ)   // 8192

typedef __attribute__((ext_vector_type(8))) short bf16x8;
typedef __attribute__((ext_vector_type(8))) short short8v;
typedef __attribute__((ext_vector_type(4))) float f32x4;
typedef __attribute__((ext_vector_type(4))) short short4v;

__device__ __forceinline__ unsigned short f2bf(float f) {
    unsigned u = __builtin_bit_cast(unsigned, f);
    u += 0x7FFF + ((u >> 16) & 1);          // RNE
    return (unsigned short)(u >> 16);
}

__device__ __forceinline__ void gload16(const void* g, void* l) {
    __builtin_amdgcn_global_load_lds(
        (const __attribute__((address_space(1))) unsigned int*)g,
        (__attribute__((address_space(3))) unsigned int*)l, 16, 0, 0);
}

// ---------------------------------------------------------------------------
// f32 -> bf16 elementwise convert (n multiple of 8)
// ---------------------------------------------------------------------------
__global__ __launch_bounds__(256) void cvt_bf16(const float* __restrict__ src,
                                                unsigned short* __restrict__ dst,
                                                int n) {
    int i = (blockIdx.x * 256 + threadIdx.x) * 8;
    if (i >= n) return;
    float4 a = *(const float4*)(src + i);
    float4 b = *(const float4*)(src + i + 4);
    short8v o;
    o[0] = (short)f2bf(a.x); o[1] = (short)f2bf(a.y);
    o[2] = (short)f2bf(a.z); o[3] = (short)f2bf(a.w);
    o[4] = (short)f2bf(b.x); o[5] = (short)f2bf(b.y);
    o[6] = (short)f2bf(b.z); o[7] = (short)f2bf(b.w);
    *(short8v*)(dst + i) = o;
}

// ---------------------------------------------------------------------------
// bf16 MFMA GEMM: C[M,N] (f32) = A[M,K] @ B[N,K]^T, A/B bf16 row-major.
// 128x128 tile, BK=64, 256 thr = 4 waves (2x2), 64x64 per wave.
// LDS tiles 128 rows x 128 B, XOR-swizzled (slot ^= row&7) via pre-swizzled
// global source + linear global_load_lds dest.
// ---------------------------------------------------------------------------
__global__ __launch_bounds__(256) void gemm_bf16(const unsigned short* __restrict__ A,
                                                 const unsigned short* __restrict__ B,
                                                 float* __restrict__ C,
                                                 int M, int N, int K) {
    __shared__ char sA[16384];
    __shared__ char sB[16384];
    const int tid  = threadIdx.x;
    const int w    = tid >> 6;
    const int lane = tid & 63;
    const int lr   = lane & 15, lg = lane >> 4;
    const int wr   = w >> 1,  wc = w & 1;
    const int m0   = blockIdx.y * 128;
    const int n0   = blockIdx.x * 128;

    f32x4 acc[4][4] = {};

    const int srow   = lane >> 3;               // row within 8-row chunk
    const int swbyte = ((lane & 7) ^ srow) << 4; // pre-swizzled byte-in-row

    for (int k0 = 0; k0 < K; k0 += 64) {
        __syncthreads();
#pragma unroll
        for (int c = 0; c < 4; ++c) {
            int chunk = w * 4 + c;              // 0..15
            int row   = chunk * 8 + srow;       // 0..127
            const char* ga = (const char*)A + ((size_t)(m0 + row) * K + k0) * 2 + swbyte;
            gload16(ga, sA + chunk * 1024);
            const char* gb = (const char*)B + ((size_t)(n0 + row) * K + k0) * 2 + swbyte;
            gload16(gb, sB + chunk * 1024);
        }
        __syncthreads();

#pragma unroll
        for (int k2 = 0; k2 < 2; ++k2) {
            bf16x8 af[4], bg[4];
#pragma unroll
            for (int f = 0; f < 4; ++f) {
                int row = wr * 64 + f * 16 + lr;
                af[f] = *(const bf16x8*)(sA + row * 128 +
                                         ((k2 * 64 + lg * 16) ^ ((row & 7) << 4)));
            }
#pragma unroll
            for (int g = 0; g < 4; ++g) {
                int row = wc * 64 + g * 16 + lr;
                bg[g] = *(const bf16x8*)(sB + row * 128 +
                                         ((k2 * 64 + lg * 16) ^ ((row & 7) << 4)));
            }
#pragma unroll
            for (int f = 0; f < 4; ++f)
#pragma unroll
                for (int g = 0; g < 4; ++g)
                    acc[f][g] = __builtin_amdgcn_mfma_f32_16x16x32_bf16(af[f], bg[g],
                                                                        acc[f][g], 0, 0, 0);
        }
    }

#pragma unroll
    for (int f = 0; f < 4; ++f)
#pragma unroll
        for (int g = 0; g < 4; ++g)
#pragma unroll
            for (int r = 0; r < 4; ++r)
                C[(size_t)(m0 + wr * 64 + f * 16 + lg * 4 + r) * N +
                  n0 + wc * 64 + g * 16 + lr] = acc[f][g][r];
}

// ---------------------------------------------------------------------------
// Fused per-head QKV projection -> bf16 q/k (q pre-scaled 0.125), vT [b,h,d,s]
// ---------------------------------------------------------------------------
__global__ __launch_bounds__(256) void qkv_kernel(const float* __restrict__ xp,
                                                  const float* __restrict__ Wq,
                                                  const float* __restrict__ Wk,
                                                  const float* __restrict__ Wv,
                                                  unsigned short* __restrict__ qb,
                                                  unsigned short* __restrict__ kb,
                                                  unsigned short* __restrict__ vT) {
    __shared__ float sX[64][65];
    __shared__ float sW[3][64][65];
    const int tid = threadIdx.x;
    const int tx = tid & 15, ty = tid >> 4;
    const int h  = blockIdx.x;
    const int r0 = blockIdx.y * 64;

    const float* Ws0 = Wq + h * 4096;
    const float* Ws1 = Wk + h * 4096;
    const float* Ws2 = Wv + h * 4096;
#pragma unroll
    for (int p = 0; p < 4; ++p) {
        int i  = tid + p * 256;
        int o  = i >> 4;
        int d4 = (i & 15) << 2;
        float4 t0 = *(const float4*)(Ws0 + o * 64 + d4);
        sW[0][o][d4 + 0] = t0.x; sW[0][o][d4 + 1] = t0.y;
        sW[0][o][d4 + 2] = t0.z; sW[0][o][d4 + 3] = t0.w;
        float4 t1 = *(const float4*)(Ws1 + o * 64 + d4);
        sW[1][o][d4 + 0] = t1.x; sW[1][o][d4 + 1] = t1.y;
        sW[1][o][d4 + 2] = t1.z; sW[1][o][d4 + 3] = t1.w;
        float4 t2 = *(const float4*)(Ws2 + o * 64 + d4);
        sW[2][o][d4 + 0] = t2.x; sW[2][o][d4 + 1] = t2.y;
        sW[2][o][d4 + 2] = t2.z; sW[2][o][d4 + 3] = t2.w;
    }
#pragma unroll
    for (int p = 0; p < 4; ++p) {
        int i  = tid + p * 256;
        int r  = i >> 4;
        int c4 = (i & 15) << 2;
        float4 t = *(const float4*)(xp + (size_t)(r0 + r) * DMODEL + h * 64 + c4);
        sX[r][c4 + 0] = t.x; sX[r][c4 + 1] = t.y;
        sX[r][c4 + 2] = t.z; sX[r][c4 + 3] = t.w;
    }
    __syncthreads();

    float aq[4][4] = {}, ak[4][4] = {}, av[4][4] = {};
#pragma unroll 4
    for (int d = 0; d < 64; ++d) {
        float x[4], wq[4], wk[4], wv[4];
#pragma unroll
        for (int i = 0; i < 4; ++i) x[i] = sX[ty * 4 + i][d];
#pragma unroll
        for (int j = 0; j < 4; ++j) {
            wq[j] = sW[0][tx * 4 + j][d];
            wk[j] = sW[1][tx * 4 + j][d];
            wv[j] = sW[2][tx * 4 + j][d];
        }
#pragma unroll
        for (int i = 0; i < 4; ++i)
#pragma unroll
            for (int j = 0; j < 4; ++j) {
                aq[i][j] = fmaf(x[i], wq[j], aq[i][j]);
                ak[i][j] = fmaf(x[i], wk[j], ak[i][j]);
                av[i][j] = fmaf(x[i], wv[j], av[i][j]);
            }
    }

    const int b  = r0 >> 10;
    const int sl = r0 & 1023;
#pragma unroll
    for (int i = 0; i < 4; ++i) {
        size_t rowbase = (size_t)(r0 + ty * 4 + i) * DMODEL + h * 64 + tx * 4;
        short4v pq, pk;
#pragma unroll
        for (int j = 0; j < 4; ++j) {
            pq[j] = (short)f2bf(aq[i][j] * 0.125f);
            pk[j] = (short)f2bf(ak[i][j]);
        }
        *(short4v*)(qb + rowbase) = pq;
        *(short4v*)(kb + rowbase) = pk;
    }
#pragma unroll
    for (int j = 0; j < 4; ++j) {
        short4v pv;
#pragma unroll
        for (int i = 0; i < 4; ++i) pv[i] = (short)f2bf(av[i][j]);
        size_t idx = ((size_t)((b * 16 + h) * 64 + tx * 4 + j)) * SEQ + sl + ty * 4;
        *(short4v*)(vT + idx) = pv;
    }
}

// ---------------------------------------------------------------------------
// MFMA flash attention -> bf16 output. 256 thr = 4 waves; wave w owns 16 rows.
// ---------------------------------------------------------------------------
__global__ __launch_bounds__(256) void attn_mfma(const unsigned short* __restrict__ qb,
                                                 const unsigned short* __restrict__ kb,
                                                 const unsigned short* __restrict__ vT,
                                                 unsigned short* __restrict__ ob) {
    __shared__ unsigned short sK[4096];
    __shared__ unsigned short sV[4096];
    __shared__ unsigned short sP[4096];

    const int tid  = threadIdx.x;
    const int w    = tid >> 6;
    const int lane = tid & 63;
    const int lr   = lane & 15;
    const int lg   = lane >> 4;
    const int bh   = blockIdx.y;
    const int b    = bh >> 4, h = bh & 15;
    const int s0   = blockIdx.x * 64;

    const unsigned short* qrow = qb + ((size_t)(b * SEQ + s0 + w * 16 + lr) * DMODEL + h * 64);
    bf16x8 qf0 = *(const bf16x8*)(qrow + lg * 8);
    bf16x8 qf1 = *(const bf16x8*)(qrow + 32 + lg * 8);

    f32x4 o_acc[4] = {};
    float m_[4], l_[4];
#pragma unroll
    for (int r = 0; r < 4; ++r) { m_[r] = -1e30f; l_[r] = 0.f; }

    const int srow = lane >> 3;
    const int ssw  = ((lane & 7) << 4) ^ (srow << 4);

    for (int kt = 0; kt < SEQ / 64; ++kt) {
        __syncthreads();
#pragma unroll
        for (int c = 0; c < 2; ++c) {
            int chunk = w * 2 + c;
            int row   = chunk * 8 + srow;
            const char* gk = (const char*)kb +
                (((size_t)(b * SEQ + kt * 64 + row) * DMODEL + h * 64) * 2) + ssw;
            gload16(gk, (char*)sK + chunk * 1024);
            const char* gv = (const char*)vT +
                (((size_t)(bh * 64 + row) * SEQ + kt * 64) * 2) + ssw;
            gload16(gv, (char*)sV + chunk * 1024);
        }
        __syncthreads();

        f32x4 s_acc[4] = {};
#pragma unroll
        for (int t = 0; t < 4; ++t) {
            int key = t * 16 + lr;
            int ksw = (key & 7) << 4;
            bf16x8 kf0 = *(const bf16x8*)((const char*)sK + key * 128 + ((lg * 16) ^ ksw));
            bf16x8 kf1 = *(const bf16x8*)((const char*)sK + key * 128 + ((64 + lg * 16) ^ ksw));
            s_acc[t] = __builtin_amdgcn_mfma_f32_16x16x32_bf16(qf0, kf0, s_acc[t], 0, 0, 0);
            s_acc[t] = __builtin_amdgcn_mfma_f32_16x16x32_bf16(qf1, kf1, s_acc[t], 0, 0, 0);
        }

        float p[4][4], alpha[4];
#pragma unroll
        for (int r = 0; r < 4; ++r) {
            float mx = fmaxf(fmaxf(s_acc[0][r], s_acc[1][r]),
                             fmaxf(s_acc[2][r], s_acc[3][r]));
#pragma unroll
            for (int off = 1; off < 16; off <<= 1)
                mx = fmaxf(mx, __shfl_xor(mx, off, 64));
            float mn = fmaxf(m_[r], mx);
            alpha[r] = __expf(m_[r] - mn);
            m_[r] = mn;
            float rs = 0.f;
#pragma unroll
            for (int t = 0; t < 4; ++t) {
                p[t][r] = __expf(s_acc[t][r] - mn);
                rs += p[t][r];
            }
#pragma unroll
            for (int off = 1; off < 16; off <<= 1)
                rs += __shfl_xor(rs, off, 64);
            l_[r] = l_[r] * alpha[r] + rs;
        }
#pragma unroll
        for (int u = 0; u < 4; ++u)
#pragma unroll
            for (int r = 0; r < 4; ++r)
                o_acc[u][r] *= alpha[r];

#pragma unroll
        for (int r = 0; r < 4; ++r) {
            int q  = lg * 4 + r;
            int rb = w * 2048 + q * 128;
            int sw = (q & 7) << 4;
#pragma unroll
            for (int t = 0; t < 4; ++t) {
                int byteo = rb + (((t * 16 + lr) * 2) ^ sw);
                *(unsigned short*)((char*)sP + byteo) = f2bf(p[t][r]);
            }
        }

#pragma unroll
        for (int k2 = 0; k2 < 2; ++k2) {
            int psw = (lr & 7) << 4;
            bf16x8 pf = *(const bf16x8*)((const char*)sP + w * 2048 + lr * 128 +
                                         ((k2 * 64 + lg * 16) ^ psw));
#pragma unroll
            for (int u = 0; u < 4; ++u) {
                int d   = u * 16 + lr;
                int vsw = (d & 7) << 4;
                bf16x8 vf = *(const bf16x8*)((const char*)sV + d * 128 +
                                             ((k2 * 64 + lg * 16) ^ vsw));
                o_acc[u] = __builtin_amdgcn_mfma_f32_16x16x32_bf16(pf, vf, o_acc[u], 0, 0, 0);
            }
        }
    }

    float inv[4];
#pragma unroll
    for (int r = 0; r < 4; ++r) inv[r] = 1.f / l_[r];
#pragma unroll
    for (int u = 0; u < 4; ++u)
#pragma unroll
        for (int r = 0; r < 4; ++r)
            ob[(size_t)(b * SEQ + s0 + w * 16 + lg * 4 + r) * DMODEL + h * 64 + u * 16 + lr] =
                f2bf(o_acc[u][r] * inv[r]);
}

// ---------------------------------------------------------------------------
extern "C" void kernel_launch(void* const* d_in, const int* in_sizes, int n_in,
                              void* d_out, int out_size, void* d_ws, size_t ws_size,
                              hipStream_t stream) {
    const float* x       = (const float*)d_in[0];
    const float* W_split = (const float*)d_in[1];
    const float* W_out   = (const float*)d_in[2];
    const float* Wq      = (const float*)d_in[3];
    const float* Wk      = (const float*)d_in[4];
    const float* Wv      = (const float*)d_in[5];
    float* out = (float*)d_out;

    float* xp = (float*)d_ws;                                       // 32 MB
    unsigned short* qb  = (unsigned short*)(xp + (size_t)ROWS * DMODEL);
    unsigned short* kb  = qb + (size_t)ROWS * DMODEL;
    unsigned short* vT  = kb + (size_t)ROWS * DMODEL;
    unsigned short* xb  = vT + (size_t)ROWS * DMODEL;               // 16 MB
    unsigned short* obb = xb;                                       // alias (xb dead post-GEMM1)
    unsigned short* wsb = xb + (size_t)ROWS * DMODEL;               // 2 MB
    unsigned short* wob = wsb + (size_t)DMODEL * DMODEL;            // 2 MB

    dim3 blk(256);

    // 0) f32 -> bf16 converts
    cvt_bf16<<<dim3(ROWS * DMODEL / 8 / 256), blk, 0, stream>>>(x, xb, ROWS * DMODEL);
    cvt_bf16<<<dim3(DMODEL * DMODEL / 8 / 256), blk, 0, stream>>>(W_split, wsb, DMODEL * DMODEL);
    cvt_bf16<<<dim3(DMODEL * DMODEL / 8 / 256), blk, 0, stream>>>(W_out, wob, DMODEL * DMODEL);

    // 1) xp = x @ W_split^T   (bf16 MFMA, f32 out)
    gemm_bf16<<<dim3(DMODEL / 128, ROWS / 128), blk, 0, stream>>>(xb, wsb, xp,
                                                                  ROWS, DMODEL, DMODEL);
    // 2) q,k,v projections -> bf16
    qkv_kernel<<<dim3(NHEAD, ROWS / 64), blk, 0, stream>>>(xp, Wq, Wk, Wv, qb, kb, vT);
    // 3) MFMA flash attention -> obb (bf16, aliases xb)
    attn_mfma<<<dim3(SEQ / 64, BATCH * NHEAD), blk, 0, stream>>>(qb, kb, vT, obb);
    // 4) out = obb @ W_out^T  (bf16 MFMA, f32 out)
    gemm_bf16<<<dim3(DMODEL / 128, ROWS / 128), blk, 0, stream>>>(obb, wob, out,
                                                                  ROWS, DMODEL, DMODEL);
}

// Round 4
// 200.366 us; speedup vs baseline: 7.1053x; 1.1743x over previous
//
#include <hip/hip_runtime.h>
#include <math.h>

#define NHEAD 16
#define HD 64
#define DMODEL 1024
#define SEQ 1024
#define BATCH 8
#define ROWS (BATCH * SEQ)   // 8192

typedef __attribute__((ext_vector_type(8))) short bf16x8;
typedef __attribute__((ext_vector_type(8))) short short8v;
typedef __attribute__((ext_vector_type(4))) float f32x4;
typedef __attribute__((ext_vector_type(4))) short short4v;

__device__ __forceinline__ unsigned short f2bf(float f) {
    unsigned u = __builtin_bit_cast(unsigned, f);
    u += 0x7FFF + ((u >> 16) & 1);          // RNE
    return (unsigned short)(u >> 16);
}

__device__ __forceinline__ float fexp2(float x) {
#if __has_builtin(__builtin_amdgcn_exp2f)
    return __builtin_amdgcn_exp2f(x);
#else
    return __expf(x * 0.6931471805599453f);
#endif
}

__device__ __forceinline__ void gload16(const void* g, void* l) {
    __builtin_amdgcn_global_load_lds(
        (const __attribute__((address_space(1))) unsigned int*)g,
        (__attribute__((address_space(3))) unsigned int*)l, 16, 0, 0);
}

// ---------------------------------------------------------------------------
// f32 -> bf16 elementwise convert (n multiple of 8)
// ---------------------------------------------------------------------------
__global__ __launch_bounds__(256) void cvt_bf16(const float* __restrict__ src,
                                                unsigned short* __restrict__ dst,
                                                int n) {
    int i = (blockIdx.x * 256 + threadIdx.x) * 8;
    if (i >= n) return;
    float4 a = *(const float4*)(src + i);
    float4 b = *(const float4*)(src + i + 4);
    short8v o;
    o[0] = (short)f2bf(a.x); o[1] = (short)f2bf(a.y);
    o[2] = (short)f2bf(a.z); o[3] = (short)f2bf(a.w);
    o[4] = (short)f2bf(b.x); o[5] = (short)f2bf(b.y);
    o[6] = (short)f2bf(b.z); o[7] = (short)f2bf(b.w);
    *(short8v*)(dst + i) = o;
}

// ---------------------------------------------------------------------------
// bf16 MFMA GEMM: C[M,N] (f32) = A[M,K] @ B[N,K]^T — unchanged from round 3
// ---------------------------------------------------------------------------
__global__ __launch_bounds__(256) void gemm_bf16(const unsigned short* __restrict__ A,
                                                 const unsigned short* __restrict__ B,
                                                 float* __restrict__ C,
                                                 int M, int N, int K) {
    __shared__ char sA[16384];
    __shared__ char sB[16384];
    const int tid  = threadIdx.x;
    const int w    = tid >> 6;
    const int lane = tid & 63;
    const int lr   = lane & 15, lg = lane >> 4;
    const int wr   = w >> 1,  wc = w & 1;
    const int m0   = blockIdx.y * 128;
    const int n0   = blockIdx.x * 128;

    f32x4 acc[4][4] = {};

    const int srow   = lane >> 3;
    const int swbyte = ((lane & 7) ^ srow) << 4;

    for (int k0 = 0; k0 < K; k0 += 64) {
        __syncthreads();
#pragma unroll
        for (int c = 0; c < 4; ++c) {
            int chunk = w * 4 + c;
            int row   = chunk * 8 + srow;
            const char* ga = (const char*)A + ((size_t)(m0 + row) * K + k0) * 2 + swbyte;
            gload16(ga, sA + chunk * 1024);
            const char* gb = (const char*)B + ((size_t)(n0 + row) * K + k0) * 2 + swbyte;
            gload16(gb, sB + chunk * 1024);
        }
        __syncthreads();

#pragma unroll
        for (int k2 = 0; k2 < 2; ++k2) {
            bf16x8 af[4], bg[4];
#pragma unroll
            for (int f = 0; f < 4; ++f) {
                int row = wr * 64 + f * 16 + lr;
                af[f] = *(const bf16x8*)(sA + row * 128 +
                                         ((k2 * 64 + lg * 16) ^ ((row & 7) << 4)));
            }
#pragma unroll
            for (int g = 0; g < 4; ++g) {
                int row = wc * 64 + g * 16 + lr;
                bg[g] = *(const bf16x8*)(sB + row * 128 +
                                         ((k2 * 64 + lg * 16) ^ ((row & 7) << 4)));
            }
#pragma unroll
            for (int f = 0; f < 4; ++f)
#pragma unroll
                for (int g = 0; g < 4; ++g)
                    acc[f][g] = __builtin_amdgcn_mfma_f32_16x16x32_bf16(af[f], bg[g],
                                                                        acc[f][g], 0, 0, 0);
        }
    }

#pragma unroll
    for (int f = 0; f < 4; ++f)
#pragma unroll
        for (int g = 0; g < 4; ++g)
#pragma unroll
            for (int r = 0; r < 4; ++r)
                C[(size_t)(m0 + wr * 64 + f * 16 + lg * 4 + r) * N +
                  n0 + wc * 64 + g * 16 + lr] = acc[f][g][r];
}

// ---------------------------------------------------------------------------
// Fused per-head QKV projection -> bf16 q/k, vT [b,h,d,s].
// q pre-scaled by 0.125*log2(e) so softmax runs in exp2 domain.
// ---------------------------------------------------------------------------
#define QSCALE 0.18033688011112042f
__global__ __launch_bounds__(256) void qkv_kernel(const float* __restrict__ xp,
                                                  const float* __restrict__ Wq,
                                                  const float* __restrict__ Wk,
                                                  const float* __restrict__ Wv,
                                                  unsigned short* __restrict__ qb,
                                                  unsigned short* __restrict__ kb,
                                                  unsigned short* __restrict__ vT) {
    __shared__ float sX[64][65];
    __shared__ float sW[3][64][65];
    const int tid = threadIdx.x;
    const int tx = tid & 15, ty = tid >> 4;
    const int h  = blockIdx.x;
    const int r0 = blockIdx.y * 64;

    const float* Ws0 = Wq + h * 4096;
    const float* Ws1 = Wk + h * 4096;
    const float* Ws2 = Wv + h * 4096;
#pragma unroll
    for (int p = 0; p < 4; ++p) {
        int i  = tid + p * 256;
        int o  = i >> 4;
        int d4 = (i & 15) << 2;
        float4 t0 = *(const float4*)(Ws0 + o * 64 + d4);
        sW[0][o][d4 + 0] = t0.x; sW[0][o][d4 + 1] = t0.y;
        sW[0][o][d4 + 2] = t0.z; sW[0][o][d4 + 3] = t0.w;
        float4 t1 = *(const float4*)(Ws1 + o * 64 + d4);
        sW[1][o][d4 + 0] = t1.x; sW[1][o][d4 + 1] = t1.y;
        sW[1][o][d4 + 2] = t1.z; sW[1][o][d4 + 3] = t1.w;
        float4 t2 = *(const float4*)(Ws2 + o * 64 + d4);
        sW[2][o][d4 + 0] = t2.x; sW[2][o][d4 + 1] = t2.y;
        sW[2][o][d4 + 2] = t2.z; sW[2][o][d4 + 3] = t2.w;
    }
#pragma unroll
    for (int p = 0; p < 4; ++p) {
        int i  = tid + p * 256;
        int r  = i >> 4;
        int c4 = (i & 15) << 2;
        float4 t = *(const float4*)(xp + (size_t)(r0 + r) * DMODEL + h * 64 + c4);
        sX[r][c4 + 0] = t.x; sX[r][c4 + 1] = t.y;
        sX[r][c4 + 2] = t.z; sX[r][c4 + 3] = t.w;
    }
    __syncthreads();

    float aq[4][4] = {}, ak[4][4] = {}, av[4][4] = {};
#pragma unroll 4
    for (int d = 0; d < 64; ++d) {
        float x[4], wq[4], wk[4], wv[4];
#pragma unroll
        for (int i = 0; i < 4; ++i) x[i] = sX[ty * 4 + i][d];
#pragma unroll
        for (int j = 0; j < 4; ++j) {
            wq[j] = sW[0][tx * 4 + j][d];
            wk[j] = sW[1][tx * 4 + j][d];
            wv[j] = sW[2][tx * 4 + j][d];
        }
#pragma unroll
        for (int i = 0; i < 4; ++i)
#pragma unroll
            for (int j = 0; j < 4; ++j) {
                aq[i][j] = fmaf(x[i], wq[j], aq[i][j]);
                ak[i][j] = fmaf(x[i], wk[j], ak[i][j]);
                av[i][j] = fmaf(x[i], wv[j], av[i][j]);
            }
    }

    const int b  = r0 >> 10;
    const int sl = r0 & 1023;
#pragma unroll
    for (int i = 0; i < 4; ++i) {
        size_t rowbase = (size_t)(r0 + ty * 4 + i) * DMODEL + h * 64 + tx * 4;
        short4v pq, pk;
#pragma unroll
        for (int j = 0; j < 4; ++j) {
            pq[j] = (short)f2bf(aq[i][j] * QSCALE);
            pk[j] = (short)f2bf(ak[i][j]);
        }
        *(short4v*)(qb + rowbase) = pq;
        *(short4v*)(kb + rowbase) = pk;
    }
#pragma unroll
    for (int j = 0; j < 4; ++j) {
        short4v pv;
#pragma unroll
        for (int i = 0; i < 4; ++i) pv[i] = (short)f2bf(av[i][j]);
        size_t idx = ((size_t)((b * 16 + h) * 64 + tx * 4 + j)) * SEQ + sl + ty * 4;
        *(short4v*)(vT + idx) = pv;
    }
}

// ---------------------------------------------------------------------------
// MFMA flash attention v2. 256 thr = 4 waves; wave w owns 32 q-rows
// (2 x 16-row groups sharing every K/V fragment read). exp2-domain softmax,
// row-sum via ones-MFMA, defer-max (THR=8) with shuffle-free ballot check.
// ---------------------------------------------------------------------------
__global__ __launch_bounds__(256) void attn_mfma(const unsigned short* __restrict__ qb,
                                                 const unsigned short* __restrict__ kb,
                                                 const unsigned short* __restrict__ vT,
                                                 unsigned short* __restrict__ ob) {
    __shared__ unsigned short sK[4096];   // 8 KB  (64 keys x 128B, swizzled)
    __shared__ unsigned short sV[4096];   // 8 KB  (V^T: 64 d x 128B, swizzled)
    __shared__ unsigned short sP[8192];   // 16 KB (4 waves x 32 q x 128B, swizzled)

    const int tid  = threadIdx.x;
    const int w    = tid >> 6;
    const int lane = tid & 63;
    const int lr   = lane & 15;
    const int lg   = lane >> 4;
    const int bh   = blockIdx.y;
    const int b    = bh >> 4, h = bh & 15;
    const int s0   = blockIdx.x * 128;

    // Q fragments for the wave's two 16-row groups
    const unsigned short* qrowA = qb + ((size_t)(b * SEQ + s0 + w * 32 + lr) * DMODEL + h * 64);
    const unsigned short* qrowB = qrowA + (size_t)16 * DMODEL;
    bf16x8 qa0 = *(const bf16x8*)(qrowA + lg * 8);
    bf16x8 qa1 = *(const bf16x8*)(qrowA + 32 + lg * 8);
    bf16x8 qb0 = *(const bf16x8*)(qrowB + lg * 8);
    bf16x8 qb1 = *(const bf16x8*)(qrowB + 32 + lg * 8);

    bf16x8 ones;
#pragma unroll
    for (int e = 0; e < 8; ++e) ones[e] = (short)0x3F80;   // bf16 1.0

    f32x4 oA[4] = {}, oB[4] = {};
    f32x4 lA = {}, lB = {};
    float mA[4], mB[4];
#pragma unroll
    for (int r = 0; r < 4; ++r) { mA[r] = -1e30f; mB[r] = -1e30f; }

    const int srow = lane >> 3;
    const int ssw  = ((lane & 7) << 4) ^ (srow << 4);

    for (int kt = 0; kt < SEQ / 64; ++kt) {
        __syncthreads();
#pragma unroll
        for (int c = 0; c < 2; ++c) {
            int chunk = w * 2 + c;
            int row   = chunk * 8 + srow;
            const char* gk = (const char*)kb +
                (((size_t)(b * SEQ + kt * 64 + row) * DMODEL + h * 64) * 2) + ssw;
            gload16(gk, (char*)sK + chunk * 1024);
            const char* gv = (const char*)vT +
                (((size_t)(bh * 64 + row) * SEQ + kt * 64) * 2) + ssw;
            gload16(gv, (char*)sV + chunk * 1024);
        }
        __syncthreads();

        // ---- S = Q K^T for both q-groups: 16 MFMA, 8 kf reads ----
        f32x4 sa[4] = {}, sb[4] = {};
#pragma unroll
        for (int t = 0; t < 4; ++t) {
            int key = t * 16 + lr;
            int ksw = (key & 7) << 4;
            bf16x8 kf0 = *(const bf16x8*)((const char*)sK + key * 128 + ((lg * 16) ^ ksw));
            bf16x8 kf1 = *(const bf16x8*)((const char*)sK + key * 128 + ((64 + lg * 16) ^ ksw));
            sa[t] = __builtin_amdgcn_mfma_f32_16x16x32_bf16(qa0, kf0, sa[t], 0, 0, 0);
            sa[t] = __builtin_amdgcn_mfma_f32_16x16x32_bf16(qa1, kf1, sa[t], 0, 0, 0);
            sb[t] = __builtin_amdgcn_mfma_f32_16x16x32_bf16(qb0, kf0, sb[t], 0, 0, 0);
            sb[t] = __builtin_amdgcn_mfma_f32_16x16x32_bf16(qb1, kf1, sb[t], 0, 0, 0);
        }

        // ---- defer-max check: per-lane local max only, no shuffles ----
        float mxa[4], mxb[4];
        int need = 0;
#pragma unroll
        for (int r = 0; r < 4; ++r) {
            mxa[r] = fmaxf(fmaxf(sa[0][r], sa[1][r]), fmaxf(sa[2][r], sa[3][r]));
            mxb[r] = fmaxf(fmaxf(sb[0][r], sb[1][r]), fmaxf(sb[2][r], sb[3][r]));
            need |= (mxa[r] > mA[r] + 8.f) | (mxb[r] > mB[r] + 8.f);
        }
        if (__any(need)) {   // rare: full reduce + rescale (always on kt==0)
#pragma unroll
            for (int r = 0; r < 4; ++r) {
                float fa = mxa[r], fb = mxb[r];
#pragma unroll
                for (int off = 1; off < 16; off <<= 1) {
                    fa = fmaxf(fa, __shfl_xor(fa, off, 64));
                    fb = fmaxf(fb, __shfl_xor(fb, off, 64));
                }
                float mnA = fmaxf(mA[r], fa);
                float mnB = fmaxf(mB[r], fb);
                float alA = fexp2(mA[r] - mnA);
                float alB = fexp2(mB[r] - mnB);
                mA[r] = mnA; mB[r] = mnB;
#pragma unroll
                for (int u = 0; u < 4; ++u) { oA[u][r] *= alA; oB[u][r] *= alB; }
                lA[r] *= alA; lB[r] *= alB;
            }
        }

        // ---- P = exp2(S - m) -> LDS (bf16, per-wave region, swizzled) ----
#pragma unroll
        for (int r = 0; r < 4; ++r) {
            int qA = lg * 4 + r;            // wave-local q row, group A (0..15)
            int qB = qA + 16;               // group B (16..31)
            int rbA = w * 4096 + qA * 128, swA = (qA & 7) << 4;
            int rbB = w * 4096 + qB * 128, swB = swA;   // (qB&7)==(qA&7)
#pragma unroll
            for (int t = 0; t < 4; ++t) {
                int co = (t * 16 + lr) * 2;
                *(unsigned short*)((char*)sP + rbA + (co ^ swA)) =
                    f2bf(fexp2(sa[t][r] - mA[r]));
                *(unsigned short*)((char*)sP + rbB + (co ^ swB)) =
                    f2bf(fexp2(sb[t][r] - mB[r]));
            }
        }

        // ---- O += P V, l += P 1 : 20 MFMA, 12 LDS reads ----
#pragma unroll
        for (int k2 = 0; k2 < 2; ++k2) {
            int pco = (k2 * 64 + lg * 16) ^ ((lr & 7) << 4);
            bf16x8 pfA = *(const bf16x8*)((const char*)sP + w * 4096 + lr * 128 + pco);
            bf16x8 pfB = *(const bf16x8*)((const char*)sP + w * 4096 + 2048 + lr * 128 + pco);
            lA = __builtin_amdgcn_mfma_f32_16x16x32_bf16(pfA, ones, lA, 0, 0, 0);
            lB = __builtin_amdgcn_mfma_f32_16x16x32_bf16(pfB, ones, lB, 0, 0, 0);
#pragma unroll
            for (int u = 0; u < 4; ++u) {
                int d = u * 16 + lr;
                bf16x8 vf = *(const bf16x8*)((const char*)sV + d * 128 +
                                             ((k2 * 64 + lg * 16) ^ ((d & 7) << 4)));
                oA[u] = __builtin_amdgcn_mfma_f32_16x16x32_bf16(pfA, vf, oA[u], 0, 0, 0);
                oB[u] = __builtin_amdgcn_mfma_f32_16x16x32_bf16(pfB, vf, oB[u], 0, 0, 0);
            }
        }
    }

    // ---- store O (bf16) ----
    float invA[4], invB[4];
#pragma unroll
    for (int r = 0; r < 4; ++r) { invA[r] = 1.f / lA[r]; invB[r] = 1.f / lB[r]; }
#pragma unroll
    for (int u = 0; u < 4; ++u)
#pragma unroll
        for (int r = 0; r < 4; ++r) {
            size_t rowA = (size_t)(b * SEQ + s0 + w * 32 + lg * 4 + r);
            ob[rowA * DMODEL + h * 64 + u * 16 + lr] = f2bf(oA[u][r] * invA[r]);
            ob[(rowA + 16) * DMODEL + h * 64 + u * 16 + lr] = f2bf(oB[u][r] * invB[r]);
        }
}

// ---------------------------------------------------------------------------
extern "C" void kernel_launch(void* const* d_in, const int* in_sizes, int n_in,
                              void* d_out, int out_size, void* d_ws, size_t ws_size,
                              hipStream_t stream) {
    const float* x       = (const float*)d_in[0];
    const float* W_split = (const float*)d_in[1];
    const float* W_out   = (const float*)d_in[2];
    const float* Wq      = (const float*)d_in[3];
    const float* Wk      = (const float*)d_in[4];
    const float* Wv      = (const float*)d_in[5];
    float* out = (float*)d_out;

    float* xp = (float*)d_ws;                                       // 32 MB
    unsigned short* qb  = (unsigned short*)(xp + (size_t)ROWS * DMODEL);
    unsigned short* kb  = qb + (size_t)ROWS * DMODEL;
    unsigned short* vT  = kb + (size_t)ROWS * DMODEL;
    unsigned short* xb  = vT + (size_t)ROWS * DMODEL;               // 16 MB
    unsigned short* obb = xb;                                       // alias (xb dead post-GEMM1)
    unsigned short* wsb = xb + (size_t)ROWS * DMODEL;               // 2 MB
    unsigned short* wob = wsb + (size_t)DMODEL * DMODEL;            // 2 MB

    dim3 blk(256);

    // 0) f32 -> bf16 converts
    cvt_bf16<<<dim3(ROWS * DMODEL / 8 / 256), blk, 0, stream>>>(x, xb, ROWS * DMODEL);
    cvt_bf16<<<dim3(DMODEL * DMODEL / 8 / 256), blk, 0, stream>>>(W_split, wsb, DMODEL * DMODEL);
    cvt_bf16<<<dim3(DMODEL * DMODEL / 8 / 256), blk, 0, stream>>>(W_out, wob, DMODEL * DMODEL);

    // 1) xp = x @ W_split^T   (bf16 MFMA, f32 out)
    gemm_bf16<<<dim3(DMODEL / 128, ROWS / 128), blk, 0, stream>>>(xb, wsb, xp,
                                                                  ROWS, DMODEL, DMODEL);
    // 2) q,k,v projections -> bf16 (q pre-scaled to exp2 domain)
    qkv_kernel<<<dim3(NHEAD, ROWS / 64), blk, 0, stream>>>(xp, Wq, Wk, Wv, qb, kb, vT);
    // 3) MFMA flash attention v2 -> obb (bf16)
    attn_mfma<<<dim3(SEQ / 128, BATCH * NHEAD), blk, 0, stream>>>(qb, kb, vT, obb);
    // 4) out = obb @ W_out^T  (bf16 MFMA, f32 out)
    gemm_bf16<<<dim3(DMODEL / 128, ROWS / 128), blk, 0, stream>>>(obb, wob, out,
                                                                  ROWS, DMODEL, DMODEL);
}

// Round 5
// 167.749 us; speedup vs baseline: 8.4869x; 1.1944x over previous
//
#include <hip/hip_runtime.h>
#include <math.h>

#define NHEAD 16
#define HD 64
#define DMODEL 1024
#define SEQ 1024
#define BATCH 8
#define ROWS (BATCH * SEQ)   // 8192

typedef __attribute__((ext_vector_type(8))) short bf16x8;
typedef __attribute__((ext_vector_type(8))) short short8v;
typedef __attribute__((ext_vector_type(4))) float f32x4;
typedef __attribute__((ext_vector_type(4))) short short4v;

__device__ __forceinline__ unsigned short f2bf(float f) {
    unsigned u = __builtin_bit_cast(unsigned, f);
    u += 0x7FFF + ((u >> 16) & 1);          // RNE
    return (unsigned short)(u >> 16);
}

__device__ __forceinline__ float fexp2(float x) {
#if __has_builtin(__builtin_amdgcn_exp2f)
    return __builtin_amdgcn_exp2f(x);
#else
    return __expf(x * 0.6931471805599453f);
#endif
}

__device__ __forceinline__ void gload16(const void* g, void* l) {
    __builtin_amdgcn_global_load_lds(
        (const __attribute__((address_space(1))) unsigned int*)g,
        (__attribute__((address_space(3))) unsigned int*)l, 16, 0, 0);
}

// ---------------------------------------------------------------------------
// f32 -> bf16 convert with scale (n multiple of 8)
// ---------------------------------------------------------------------------
__global__ __launch_bounds__(256) void cvt_bf16(const float* __restrict__ src,
                                                unsigned short* __restrict__ dst,
                                                int n, float scale) {
    int i = (blockIdx.x * 256 + threadIdx.x) * 8;
    if (i >= n) return;
    float4 a = *(const float4*)(src + i);
    float4 b = *(const float4*)(src + i + 4);
    short8v o;
    o[0] = (short)f2bf(a.x * scale); o[1] = (short)f2bf(a.y * scale);
    o[2] = (short)f2bf(a.z * scale); o[3] = (short)f2bf(a.w * scale);
    o[4] = (short)f2bf(b.x * scale); o[5] = (short)f2bf(b.y * scale);
    o[6] = (short)f2bf(b.z * scale); o[7] = (short)f2bf(b.w * scale);
    *(short8v*)(dst + i) = o;
}

// ---------------------------------------------------------------------------
// bf16 MFMA GEMM, 2-phase pipelined: C = A[M,K] @ B[N,K]^T.
// 128x128 tile, BK=64, double-buffered LDS (64 KB). BF16OUT selects C dtype.
// ---------------------------------------------------------------------------
template <bool BF16OUT>
__global__ __launch_bounds__(256) void gemm_bf16(const unsigned short* __restrict__ A,
                                                 const unsigned short* __restrict__ B,
                                                 float* __restrict__ Cf,
                                                 unsigned short* __restrict__ Cb,
                                                 int M, int N, int K) {
    __shared__ char sA[2][16384];
    __shared__ char sB[2][16384];
    const int tid  = threadIdx.x;
    const int w    = tid >> 6;
    const int lane = tid & 63;
    const int lr   = lane & 15, lg = lane >> 4;
    const int wr   = w >> 1,  wc = w & 1;
    const int m0   = blockIdx.y * 128;
    const int n0   = blockIdx.x * 128;

    f32x4 acc[4][4] = {};

    const int srow   = lane >> 3;
    const int swbyte = ((lane & 7) ^ srow) << 4;
    const int nt     = K / 64;

#define GEMM_STAGE(buf, k0)                                                        \
    {                                                                              \
        _Pragma("unroll")                                                          \
        for (int c = 0; c < 4; ++c) {                                              \
            int chunk = w * 4 + c;                                                 \
            int row   = chunk * 8 + srow;                                          \
            gload16((const char*)A + ((size_t)(m0 + row) * K + (k0)) * 2 + swbyte, \
                    sA[buf] + chunk * 1024);                                       \
            gload16((const char*)B + ((size_t)(n0 + row) * K + (k0)) * 2 + swbyte, \
                    sB[buf] + chunk * 1024);                                       \
        }                                                                          \
    }

    GEMM_STAGE(0, 0);
    __syncthreads();

    int cur = 0;
    for (int t = 0; t < nt; ++t) {
        if (t + 1 < nt) GEMM_STAGE(cur ^ 1, (t + 1) * 64);

#pragma unroll
        for (int k2 = 0; k2 < 2; ++k2) {
            bf16x8 af[4], bg[4];
#pragma unroll
            for (int f = 0; f < 4; ++f) {
                int row = wr * 64 + f * 16 + lr;
                af[f] = *(const bf16x8*)(sA[cur] + row * 128 +
                                         ((k2 * 64 + lg * 16) ^ ((row & 7) << 4)));
            }
#pragma unroll
            for (int g = 0; g < 4; ++g) {
                int row = wc * 64 + g * 16 + lr;
                bg[g] = *(const bf16x8*)(sB[cur] + row * 128 +
                                         ((k2 * 64 + lg * 16) ^ ((row & 7) << 4)));
            }
#pragma unroll
            for (int f = 0; f < 4; ++f)
#pragma unroll
                for (int g = 0; g < 4; ++g)
                    acc[f][g] = __builtin_amdgcn_mfma_f32_16x16x32_bf16(af[f], bg[g],
                                                                        acc[f][g], 0, 0, 0);
        }
        __syncthreads();
        cur ^= 1;
    }
#undef GEMM_STAGE

#pragma unroll
    for (int f = 0; f < 4; ++f)
#pragma unroll
        for (int g = 0; g < 4; ++g)
#pragma unroll
            for (int r = 0; r < 4; ++r) {
                size_t idx = (size_t)(m0 + wr * 64 + f * 16 + lg * 4 + r) * N +
                             n0 + wc * 64 + g * 16 + lr;
                if (BF16OUT) Cb[idx] = f2bf(acc[f][g][r]);
                else         Cf[idx] = acc[f][g][r];
            }
}

// ---------------------------------------------------------------------------
// MFMA QKV projection. Block = (head, 128-row tile), 4 waves.
// q = xpb @ WqT (QSCALE pre-folded into wqb), k likewise, v -> vT [b,h,d,s].
// ---------------------------------------------------------------------------
__global__ __launch_bounds__(256) void qkv_mfma(const unsigned short* __restrict__ xpb,
                                                const unsigned short* __restrict__ wqb,
                                                const unsigned short* __restrict__ wkb,
                                                const unsigned short* __restrict__ wvb,
                                                unsigned short* __restrict__ qb,
                                                unsigned short* __restrict__ kb,
                                                unsigned short* __restrict__ vT) {
    __shared__ char sX[16384];     // 128 rows x 128 B, swizzled
    __shared__ char sW[3][8192];   // 64 rows x 128 B each, swizzled
    const int tid  = threadIdx.x;
    const int w    = tid >> 6;
    const int lane = tid & 63;
    const int lr   = lane & 15, lg = lane >> 4;
    const int h    = blockIdx.x;
    const int r0   = blockIdx.y * 128;

    const int srow   = lane >> 3;
    const int swbyte = ((lane & 7) ^ srow) << 4;

#pragma unroll
    for (int i = 0; i < 10; ++i) {
        int chunk = w * 10 + i;                 // 0..39
        if (chunk < 16) {
            int row = chunk * 8 + srow;
            gload16((const char*)xpb + ((size_t)(r0 + row) * DMODEL + h * 64) * 2 + swbyte,
                    sX + chunk * 1024);
        } else {
            int wi = (chunk - 16) >> 3;         // 0..2
            int rc = (chunk - 16) & 7;          // 0..7
            int row = rc * 8 + srow;
            const unsigned short* ws = (wi == 0) ? wqb : (wi == 1) ? wkb : wvb;
            gload16((const char*)ws + ((size_t)(h * 64 + row) * 64) * 2 + swbyte,
                    sW[wi] + rc * 1024);
        }
    }
    __syncthreads();

    f32x4 acc[3][2][4] = {};   // proj, row-frag, out-frag
#pragma unroll
    for (int k2 = 0; k2 < 2; ++k2) {
        bf16x8 af[2];
#pragma unroll
        for (int f = 0; f < 2; ++f) {
            int row = w * 32 + f * 16 + lr;
            af[f] = *(const bf16x8*)(sX + row * 128 +
                                     ((k2 * 64 + lg * 16) ^ ((row & 7) << 4)));
        }
#pragma unroll
        for (int p = 0; p < 3; ++p)
#pragma unroll
            for (int g = 0; g < 4; ++g) {
                int row = g * 16 + lr;
                bf16x8 bg = *(const bf16x8*)(sW[p] + row * 128 +
                                             ((k2 * 64 + lg * 16) ^ ((row & 7) << 4)));
#pragma unroll
                for (int f = 0; f < 2; ++f)
                    acc[p][f][g] = __builtin_amdgcn_mfma_f32_16x16x32_bf16(af[f], bg,
                                                                           acc[p][f][g], 0, 0, 0);
            }
    }

    const int b  = r0 >> 10;
    const int sl = r0 & 1023;
#pragma unroll
    for (int f = 0; f < 2; ++f)
#pragma unroll
        for (int g = 0; g < 4; ++g) {
#pragma unroll
            for (int r = 0; r < 4; ++r) {
                size_t idx = (size_t)(r0 + w * 32 + f * 16 + lg * 4 + r) * DMODEL +
                             h * 64 + g * 16 + lr;
                qb[idx] = f2bf(acc[0][f][g][r]);
                kb[idx] = f2bf(acc[1][f][g][r]);
            }
            short4v pv;
#pragma unroll
            for (int r = 0; r < 4; ++r) pv[r] = (short)f2bf(acc[2][f][g][r]);
            size_t o = (size_t)(b * 16 + h) * 64 + g * 16 + lr;
            *(short4v*)(vT + o * SEQ + sl + w * 32 + f * 16 + lg * 4) = pv;
        }
}

// ---------------------------------------------------------------------------
// MFMA flash attention v3: double-buffered K/V prefetch, one barrier/iter.
// 4 waves x 32 q-rows; exp2 softmax, ones-MFMA row-sum, defer-max.
// ---------------------------------------------------------------------------
__global__ __launch_bounds__(256) void attn_mfma(const unsigned short* __restrict__ qb,
                                                 const unsigned short* __restrict__ kb,
                                                 const unsigned short* __restrict__ vT,
                                                 unsigned short* __restrict__ ob) {
    __shared__ unsigned short sK[2][4096];   // 2 x 8 KB
    __shared__ unsigned short sV[2][4096];   // 2 x 8 KB
    __shared__ unsigned short sP[8192];      // 16 KB, wave-private regions

    const int tid  = threadIdx.x;
    const int w    = tid >> 6;
    const int lane = tid & 63;
    const int lr   = lane & 15;
    const int lg   = lane >> 4;
    const int bh   = blockIdx.y;
    const int b    = bh >> 4, h = bh & 15;
    const int s0   = blockIdx.x * 128;

    const unsigned short* qrowA = qb + ((size_t)(b * SEQ + s0 + w * 32 + lr) * DMODEL + h * 64);
    const unsigned short* qrowB = qrowA + (size_t)16 * DMODEL;
    bf16x8 qa0 = *(const bf16x8*)(qrowA + lg * 8);
    bf16x8 qa1 = *(const bf16x8*)(qrowA + 32 + lg * 8);
    bf16x8 qb0 = *(const bf16x8*)(qrowB + lg * 8);
    bf16x8 qb1 = *(const bf16x8*)(qrowB + 32 + lg * 8);

    bf16x8 ones;
#pragma unroll
    for (int e = 0; e < 8; ++e) ones[e] = (short)0x3F80;

    f32x4 oA[4] = {}, oB[4] = {};
    f32x4 lA = {}, lB = {};
    float mA[4], mB[4];
#pragma unroll
    for (int r = 0; r < 4; ++r) { mA[r] = -1e30f; mB[r] = -1e30f; }

    const int srow = lane >> 3;
    const int ssw  = ((lane & 7) << 4) ^ (srow << 4);

#define ATTN_STAGE(buf, kt)                                                          \
    {                                                                                \
        _Pragma("unroll")                                                            \
        for (int c = 0; c < 2; ++c) {                                                \
            int chunk = w * 2 + c;                                                   \
            int row   = chunk * 8 + srow;                                            \
            gload16((const char*)kb +                                                \
                        (((size_t)(b * SEQ + (kt) * 64 + row) * DMODEL + h * 64) * 2) + ssw, \
                    (char*)sK[buf] + chunk * 1024);                                  \
            gload16((const char*)vT +                                                \
                        (((size_t)(bh * 64 + row) * SEQ + (kt) * 64) * 2) + ssw,     \
                    (char*)sV[buf] + chunk * 1024);                                  \
        }                                                                            \
    }

    ATTN_STAGE(0, 0);
    __syncthreads();

    int cur = 0;
    for (int kt = 0; kt < SEQ / 64; ++kt) {
        if (kt + 1 < SEQ / 64) ATTN_STAGE(cur ^ 1, kt + 1);

        // ---- S = Q K^T for both q-groups ----
        f32x4 sa[4] = {}, sb[4] = {};
#pragma unroll
        for (int t = 0; t < 4; ++t) {
            int key = t * 16 + lr;
            int ksw = (key & 7) << 4;
            bf16x8 kf0 = *(const bf16x8*)((const char*)sK[cur] + key * 128 + ((lg * 16) ^ ksw));
            bf16x8 kf1 = *(const bf16x8*)((const char*)sK[cur] + key * 128 + ((64 + lg * 16) ^ ksw));
            sa[t] = __builtin_amdgcn_mfma_f32_16x16x32_bf16(qa0, kf0, sa[t], 0, 0, 0);
            sa[t] = __builtin_amdgcn_mfma_f32_16x16x32_bf16(qa1, kf1, sa[t], 0, 0, 0);
            sb[t] = __builtin_amdgcn_mfma_f32_16x16x32_bf16(qb0, kf0, sb[t], 0, 0, 0);
            sb[t] = __builtin_amdgcn_mfma_f32_16x16x32_bf16(qb1, kf1, sb[t], 0, 0, 0);
        }

        // ---- defer-max check (no shuffles in steady state) ----
        float mxa[4], mxb[4];
        int need = 0;
#pragma unroll
        for (int r = 0; r < 4; ++r) {
            mxa[r] = fmaxf(fmaxf(sa[0][r], sa[1][r]), fmaxf(sa[2][r], sa[3][r]));
            mxb[r] = fmaxf(fmaxf(sb[0][r], sb[1][r]), fmaxf(sb[2][r], sb[3][r]));
            need |= (mxa[r] > mA[r] + 8.f) | (mxb[r] > mB[r] + 8.f);
        }
        if (__any(need)) {
#pragma unroll
            for (int r = 0; r < 4; ++r) {
                float fa = mxa[r], fb = mxb[r];
#pragma unroll
                for (int off = 1; off < 16; off <<= 1) {
                    fa = fmaxf(fa, __shfl_xor(fa, off, 64));
                    fb = fmaxf(fb, __shfl_xor(fb, off, 64));
                }
                float mnA = fmaxf(mA[r], fa);
                float mnB = fmaxf(mB[r], fb);
                float alA = fexp2(mA[r] - mnA);
                float alB = fexp2(mB[r] - mnB);
                mA[r] = mnA; mB[r] = mnB;
#pragma unroll
                for (int u = 0; u < 4; ++u) { oA[u][r] *= alA; oB[u][r] *= alB; }
                lA[r] *= alA; lB[r] *= alB;
            }
        }

        // ---- P = exp2(S - m) -> LDS (wave-private, swizzled) ----
#pragma unroll
        for (int r = 0; r < 4; ++r) {
            int qA  = lg * 4 + r;
            int rbA = w * 4096 + qA * 128;
            int swA = (qA & 7) << 4;
#pragma unroll
            for (int t = 0; t < 4; ++t) {
                int co = (t * 16 + lr) * 2;
                *(unsigned short*)((char*)sP + rbA + (co ^ swA)) =
                    f2bf(fexp2(sa[t][r] - mA[r]));
                *(unsigned short*)((char*)sP + rbA + 2048 + (co ^ swA)) =
                    f2bf(fexp2(sb[t][r] - mB[r]));
            }
        }

        // ---- O += P V, l += P 1 ----
#pragma unroll
        for (int k2 = 0; k2 < 2; ++k2) {
            int pco = (k2 * 64 + lg * 16) ^ ((lr & 7) << 4);
            bf16x8 pfA = *(const bf16x8*)((const char*)sP + w * 4096 + lr * 128 + pco);
            bf16x8 pfB = *(const bf16x8*)((const char*)sP + w * 4096 + 2048 + lr * 128 + pco);
            lA = __builtin_amdgcn_mfma_f32_16x16x32_bf16(pfA, ones, lA, 0, 0, 0);
            lB = __builtin_amdgcn_mfma_f32_16x16x32_bf16(pfB, ones, lB, 0, 0, 0);
#pragma unroll
            for (int u = 0; u < 4; ++u) {
                int d = u * 16 + lr;
                bf16x8 vf = *(const bf16x8*)((const char*)sV[cur] + d * 128 +
                                             ((k2 * 64 + lg * 16) ^ ((d & 7) << 4)));
                oA[u] = __builtin_amdgcn_mfma_f32_16x16x32_bf16(pfA, vf, oA[u], 0, 0, 0);
                oB[u] = __builtin_amdgcn_mfma_f32_16x16x32_bf16(pfB, vf, oB[u], 0, 0, 0);
            }
        }
        __syncthreads();
        cur ^= 1;
    }
#undef ATTN_STAGE

    float invA[4], invB[4];
#pragma unroll
    for (int r = 0; r < 4; ++r) { invA[r] = 1.f / lA[r]; invB[r] = 1.f / lB[r]; }
#pragma unroll
    for (int u = 0; u < 4; ++u)
#pragma unroll
        for (int r = 0; r < 4; ++r) {
            size_t rowA = (size_t)(b * SEQ + s0 + w * 32 + lg * 4 + r);
            ob[rowA * DMODEL + h * 64 + u * 16 + lr] = f2bf(oA[u][r] * invA[r]);
            ob[(rowA + 16) * DMODEL + h * 64 + u * 16 + lr] = f2bf(oB[u][r] * invB[r]);
        }
}

// ---------------------------------------------------------------------------
#define QSCALE 0.18033688011112042f
extern "C" void kernel_launch(void* const* d_in, const int* in_sizes, int n_in,
                              void* d_out, int out_size, void* d_ws, size_t ws_size,
                              hipStream_t stream) {
    const float* x       = (const float*)d_in[0];
    const float* W_split = (const float*)d_in[1];
    const float* W_out   = (const float*)d_in[2];
    const float* Wq      = (const float*)d_in[3];
    const float* Wk      = (const float*)d_in[4];
    const float* Wv      = (const float*)d_in[5];
    float* out = (float*)d_out;

    unsigned short* xb  = (unsigned short*)d_ws;                    // 16 MB
    unsigned short* obb = xb;                                       // alias (xb dead post-GEMM1... attn)
    unsigned short* wsb = xb + (size_t)ROWS * DMODEL;               // 2 MB
    unsigned short* wob = wsb + (size_t)DMODEL * DMODEL;            // 2 MB
    unsigned short* xpb = wob + (size_t)DMODEL * DMODEL;            // 16 MB
    unsigned short* qbuf= xpb + (size_t)ROWS * DMODEL;              // 16 MB
    unsigned short* kbuf= qbuf + (size_t)ROWS * DMODEL;             // 16 MB
    unsigned short* vT  = kbuf + (size_t)ROWS * DMODEL;             // 16 MB
    unsigned short* wqb = vT + (size_t)ROWS * DMODEL;               // 128 KB
    unsigned short* wkb = wqb + (size_t)NHEAD * HD * HD;
    unsigned short* wvb = wkb + (size_t)NHEAD * HD * HD;

    dim3 blk(256);

    // 0) f32 -> bf16 converts (QSCALE folded into Wq)
    cvt_bf16<<<dim3(ROWS * DMODEL / 2048), blk, 0, stream>>>(x, xb, ROWS * DMODEL, 1.f);
    cvt_bf16<<<dim3(DMODEL * DMODEL / 2048), blk, 0, stream>>>(W_split, wsb, DMODEL * DMODEL, 1.f);
    cvt_bf16<<<dim3(DMODEL * DMODEL / 2048), blk, 0, stream>>>(W_out, wob, DMODEL * DMODEL, 1.f);
    cvt_bf16<<<dim3(NHEAD * HD * HD / 2048), blk, 0, stream>>>(Wq, wqb, NHEAD * HD * HD, QSCALE);
    cvt_bf16<<<dim3(NHEAD * HD * HD / 2048), blk, 0, stream>>>(Wk, wkb, NHEAD * HD * HD, 1.f);
    cvt_bf16<<<dim3(NHEAD * HD * HD / 2048), blk, 0, stream>>>(Wv, wvb, NHEAD * HD * HD, 1.f);

    // 1) xpb = bf16( x @ W_split^T )
    gemm_bf16<true><<<dim3(DMODEL / 128, ROWS / 128), blk, 0, stream>>>(
        xb, wsb, nullptr, xpb, ROWS, DMODEL, DMODEL);
    // 2) q,k,v projections (MFMA)
    qkv_mfma<<<dim3(NHEAD, ROWS / 128), blk, 0, stream>>>(xpb, wqb, wkb, wvb,
                                                          qbuf, kbuf, vT);
    // 3) MFMA flash attention v3 -> obb (bf16)
    attn_mfma<<<dim3(SEQ / 128, BATCH * NHEAD), blk, 0, stream>>>(qbuf, kbuf, vT, obb);
    // 4) out = obb @ W_out^T (f32)
    gemm_bf16<false><<<dim3(DMODEL / 128, ROWS / 128), blk, 0, stream>>>(
        obb, wob, out, nullptr, ROWS, DMODEL, DMODEL);
}

// Round 6
// 148.547 us; speedup vs baseline: 9.5840x; 1.1293x over previous
//
#include <hip/hip_runtime.h>
#include <math.h>

#define NHEAD 16
#define HD 64
#define DMODEL 1024
#define SEQ 1024
#define BATCH 8
#define ROWS (BATCH * SEQ)   // 8192

typedef __attribute__((ext_vector_type(8))) short bf16x8;
typedef __attribute__((ext_vector_type(8))) short short8v;
typedef __attribute__((ext_vector_type(4))) float f32x4;
typedef __attribute__((ext_vector_type(16))) float f32x16;
typedef __attribute__((ext_vector_type(4))) short short4v;
typedef __attribute__((ext_vector_type(4))) unsigned int uint32x4;

__device__ __forceinline__ unsigned short f2bf(float f) {
    unsigned u = __builtin_bit_cast(unsigned, f);
    u += 0x7FFF + ((u >> 16) & 1);          // RNE
    return (unsigned short)(u >> 16);
}

__device__ __forceinline__ float fexp2(float x) {
#if __has_builtin(__builtin_amdgcn_exp2f)
    return __builtin_amdgcn_exp2f(x);
#else
    return __expf(x * 0.6931471805599453f);
#endif
}

__device__ __forceinline__ void gload16(const void* g, void* l) {
    __builtin_amdgcn_global_load_lds(
        (const __attribute__((address_space(1))) unsigned int*)g,
        (__attribute__((address_space(3))) unsigned int*)l, 16, 0, 0);
}

// ---------------------------------------------------------------------------
// f32 -> bf16 convert with scale (n multiple of 8)
// ---------------------------------------------------------------------------
__global__ __launch_bounds__(256) void cvt_bf16(const float* __restrict__ src,
                                                unsigned short* __restrict__ dst,
                                                int n, float scale) {
    int i = (blockIdx.x * 256 + threadIdx.x) * 8;
    if (i >= n) return;
    float4 a = *(const float4*)(src + i);
    float4 b = *(const float4*)(src + i + 4);
    short8v o;
    o[0] = (short)f2bf(a.x * scale); o[1] = (short)f2bf(a.y * scale);
    o[2] = (short)f2bf(a.z * scale); o[3] = (short)f2bf(a.w * scale);
    o[4] = (short)f2bf(b.x * scale); o[5] = (short)f2bf(b.y * scale);
    o[6] = (short)f2bf(b.z * scale); o[7] = (short)f2bf(b.w * scale);
    *(short8v*)(dst + i) = o;
}

// ---------------------------------------------------------------------------
// bf16 MFMA GEMM, 2-phase pipelined: C = A[M,K] @ B[N,K]^T. (unchanged)
// ---------------------------------------------------------------------------
template <bool BF16OUT>
__global__ __launch_bounds__(256) void gemm_bf16(const unsigned short* __restrict__ A,
                                                 const unsigned short* __restrict__ B,
                                                 float* __restrict__ Cf,
                                                 unsigned short* __restrict__ Cb,
                                                 int M, int N, int K) {
    __shared__ char sA[2][16384];
    __shared__ char sB[2][16384];
    const int tid  = threadIdx.x;
    const int w    = tid >> 6;
    const int lane = tid & 63;
    const int lr   = lane & 15, lg = lane >> 4;
    const int wr   = w >> 1,  wc = w & 1;
    const int m0   = blockIdx.y * 128;
    const int n0   = blockIdx.x * 128;

    f32x4 acc[4][4] = {};

    const int srow   = lane >> 3;
    const int swbyte = ((lane & 7) ^ srow) << 4;
    const int nt     = K / 64;

#define GEMM_STAGE(buf, k0)                                                        \
    {                                                                              \
        _Pragma("unroll")                                                          \
        for (int c = 0; c < 4; ++c) {                                              \
            int chunk = w * 4 + c;                                                 \
            int row   = chunk * 8 + srow;                                          \
            gload16((const char*)A + ((size_t)(m0 + row) * K + (k0)) * 2 + swbyte, \
                    sA[buf] + chunk * 1024);                                       \
            gload16((const char*)B + ((size_t)(n0 + row) * K + (k0)) * 2 + swbyte, \
                    sB[buf] + chunk * 1024);                                       \
        }                                                                          \
    }

    GEMM_STAGE(0, 0);
    __syncthreads();

    int cur = 0;
    for (int t = 0; t < nt; ++t) {
        if (t + 1 < nt) GEMM_STAGE(cur ^ 1, (t + 1) * 64);

#pragma unroll
        for (int k2 = 0; k2 < 2; ++k2) {
            bf16x8 af[4], bg[4];
#pragma unroll
            for (int f = 0; f < 4; ++f) {
                int row = wr * 64 + f * 16 + lr;
                af[f] = *(const bf16x8*)(sA[cur] + row * 128 +
                                         ((k2 * 64 + lg * 16) ^ ((row & 7) << 4)));
            }
#pragma unroll
            for (int g = 0; g < 4; ++g) {
                int row = wc * 64 + g * 16 + lr;
                bg[g] = *(const bf16x8*)(sB[cur] + row * 128 +
                                         ((k2 * 64 + lg * 16) ^ ((row & 7) << 4)));
            }
#pragma unroll
            for (int f = 0; f < 4; ++f)
#pragma unroll
                for (int g = 0; g < 4; ++g)
                    acc[f][g] = __builtin_amdgcn_mfma_f32_16x16x32_bf16(af[f], bg[g],
                                                                        acc[f][g], 0, 0, 0);
        }
        __syncthreads();
        cur ^= 1;
    }
#undef GEMM_STAGE

#pragma unroll
    for (int f = 0; f < 4; ++f)
#pragma unroll
        for (int g = 0; g < 4; ++g)
#pragma unroll
            for (int r = 0; r < 4; ++r) {
                size_t idx = (size_t)(m0 + wr * 64 + f * 16 + lg * 4 + r) * N +
                             n0 + wc * 64 + g * 16 + lr;
                if (BF16OUT) Cb[idx] = f2bf(acc[f][g][r]);
                else         Cf[idx] = acc[f][g][r];
            }
}

// ---------------------------------------------------------------------------
// MFMA QKV projection (unchanged from round 5)
// ---------------------------------------------------------------------------
__global__ __launch_bounds__(256) void qkv_mfma(const unsigned short* __restrict__ xpb,
                                                const unsigned short* __restrict__ wqb,
                                                const unsigned short* __restrict__ wkb,
                                                const unsigned short* __restrict__ wvb,
                                                unsigned short* __restrict__ qb,
                                                unsigned short* __restrict__ kb,
                                                unsigned short* __restrict__ vT) {
    __shared__ char sX[16384];
    __shared__ char sW[3][8192];
    const int tid  = threadIdx.x;
    const int w    = tid >> 6;
    const int lane = tid & 63;
    const int lr   = lane & 15, lg = lane >> 4;
    const int h    = blockIdx.x;
    const int r0   = blockIdx.y * 128;

    const int srow   = lane >> 3;
    const int swbyte = ((lane & 7) ^ srow) << 4;

#pragma unroll
    for (int i = 0; i < 10; ++i) {
        int chunk = w * 10 + i;
        if (chunk < 16) {
            int row = chunk * 8 + srow;
            gload16((const char*)xpb + ((size_t)(r0 + row) * DMODEL + h * 64) * 2 + swbyte,
                    sX + chunk * 1024);
        } else {
            int wi = (chunk - 16) >> 3;
            int rc = (chunk - 16) & 7;
            int row = rc * 8 + srow;
            const unsigned short* ws = (wi == 0) ? wqb : (wi == 1) ? wkb : wvb;
            gload16((const char*)ws + ((size_t)(h * 64 + row) * 64) * 2 + swbyte,
                    sW[wi] + rc * 1024);
        }
    }
    __syncthreads();

    f32x4 acc[3][2][4] = {};
#pragma unroll
    for (int k2 = 0; k2 < 2; ++k2) {
        bf16x8 af[2];
#pragma unroll
        for (int f = 0; f < 2; ++f) {
            int row = w * 32 + f * 16 + lr;
            af[f] = *(const bf16x8*)(sX + row * 128 +
                                     ((k2 * 64 + lg * 16) ^ ((row & 7) << 4)));
        }
#pragma unroll
        for (int p = 0; p < 3; ++p)
#pragma unroll
            for (int g = 0; g < 4; ++g) {
                int row = g * 16 + lr;
                bf16x8 bg = *(const bf16x8*)(sW[p] + row * 128 +
                                             ((k2 * 64 + lg * 16) ^ ((row & 7) << 4)));
#pragma unroll
                for (int f = 0; f < 2; ++f)
                    acc[p][f][g] = __builtin_amdgcn_mfma_f32_16x16x32_bf16(af[f], bg,
                                                                           acc[p][f][g], 0, 0, 0);
            }
    }

    const int b  = r0 >> 10;
    const int sl = r0 & 1023;
#pragma unroll
    for (int f = 0; f < 2; ++f)
#pragma unroll
        for (int g = 0; g < 4; ++g) {
#pragma unroll
            for (int r = 0; r < 4; ++r) {
                size_t idx = (size_t)(r0 + w * 32 + f * 16 + lg * 4 + r) * DMODEL +
                             h * 64 + g * 16 + lr;
                qb[idx] = f2bf(acc[0][f][g][r]);
                kb[idx] = f2bf(acc[1][f][g][r]);
            }
            short4v pv;
#pragma unroll
            for (int r = 0; r < 4; ++r) pv[r] = (short)f2bf(acc[2][f][g][r]);
            size_t o = (size_t)(b * 16 + h) * 64 + g * 16 + lr;
            *(short4v*)(vT + o * SEQ + sl + w * 32 + f * 16 + lg * 4) = pv;
        }
}

// ---------------------------------------------------------------------------
// MFMA flash attention v4: 32x32x16 swapped-operand structure.
// S^T = K·Q^T (lane owns q-col), in-register softmax, P->PV operand via
// cvt_pk + permlane32_swap (no P LDS round-trip), O accumulated as O^T.
// ---------------------------------------------------------------------------
__global__ __launch_bounds__(256) void attn_mfma(const unsigned short* __restrict__ qb,
                                                 const unsigned short* __restrict__ kb,
                                                 const unsigned short* __restrict__ vT,
                                                 unsigned short* __restrict__ ob) {
    __shared__ unsigned short sK[2][4096];   // 2 x 8 KB: 64 keys x 128B (swizzled)
    __shared__ unsigned short sV[2][4096];   // 2 x 8 KB: V^T 64 d x 128B (swizzled)

    const int tid  = threadIdx.x;
    const int w    = tid >> 6;
    const int lane = tid & 63;
    const int ql   = lane & 31;          // q column owned by this lane
    const int hl   = lane >> 5;          // half index
    const int bh   = blockIdx.y;
    const int b    = bh >> 4, h = bh & 15;
    const int s0   = blockIdx.x * 128;

    // Q B-fragments: col=q(ql), k-elems d = 16s + 8*hl + e
    const unsigned short* qrow = qb + ((size_t)(b * SEQ + s0 + w * 32 + ql) * DMODEL + h * 64);
    bf16x8 qf[4];
#pragma unroll
    for (int s = 0; s < 4; ++s)
        qf[s] = *(const bf16x8*)(qrow + 16 * s + 8 * hl);

    f32x16 acc0 = {}, acc1 = {};         // O^T: d-tiles [0..31],[32..63] x q
    float m_ = -1e30f, l_ = 0.f;

    const int srow = lane >> 3;
    const int ssw  = ((lane & 7) << 4) ^ (srow << 4);
    const int swz  = (ql & 7) << 4;      // read-side swizzle (rows 32+ql share it)

#define ATTN_STAGE(buf, kt)                                                          \
    {                                                                                \
        _Pragma("unroll")                                                            \
        for (int c = 0; c < 2; ++c) {                                                \
            int chunk = w * 2 + c;                                                   \
            int row   = chunk * 8 + srow;                                            \
            gload16((const char*)kb +                                                \
                        (((size_t)(b * SEQ + (kt) * 64 + row) * DMODEL + h * 64) * 2) + ssw, \
                    (char*)sK[buf] + chunk * 1024);                                  \
            gload16((const char*)vT +                                                \
                        (((size_t)(bh * 64 + row) * SEQ + (kt) * 64) * 2) + ssw,     \
                    (char*)sV[buf] + chunk * 1024);                                  \
        }                                                                            \
    }

    ATTN_STAGE(0, 0);
    __syncthreads();

    int cur = 0;
    for (int kt = 0; kt < SEQ / 64; ++kt) {
        if (kt + 1 < SEQ / 64) ATTN_STAGE(cur ^ 1, kt + 1);

        // ---- S^T = K·Q^T: key-tiles t=0 (rows ql), t=1 (rows 32+ql) ----
        f32x16 st0 = {}, st1 = {};
#pragma unroll
        for (int s = 0; s < 4; ++s) {
            int byo = (32 * s + 16 * hl) ^ swz;
            bf16x8 kf0 = *(const bf16x8*)((const char*)sK[cur] + ql * 128 + byo);
            bf16x8 kf1 = *(const bf16x8*)((const char*)sK[cur] + (32 + ql) * 128 + byo);
            st0 = __builtin_amdgcn_mfma_f32_32x32x16_bf16(kf0, qf[s], st0, 0, 0, 0);
            st1 = __builtin_amdgcn_mfma_f32_32x32x16_bf16(kf1, qf[s], st1, 0, 0, 0);
        }

        // ---- defer-max check (lane-local; key rows are lane-local) ----
        float mx = st0[0];
#pragma unroll
        for (int i = 1; i < 16; ++i) mx = fmaxf(mx, st0[i]);
#pragma unroll
        for (int i = 0; i < 16; ++i) mx = fmaxf(mx, st1[i]);
        if (__any(mx > m_ + 8.f)) {
            float rm = fmaxf(mx, __shfl_xor(mx, 32, 64));
            float mn = fmaxf(m_, rm);
            float al = fexp2(m_ - mn);
            m_ = mn;
            l_ *= al;
#pragma unroll
            for (int i = 0; i < 16; ++i) { acc0[i] *= al; acc1[i] *= al; }
        }

        // ---- P = exp2(S^T - m), pack to bf16 pairs, swap-assemble B-frags ----
        bf16x8 pf[4];
        float lsum = 0.f;
#define TILE_P(stv, PF0, PF1)                                                       \
        {                                                                           \
            float p_[16];                                                           \
            _Pragma("unroll")                                                       \
            for (int i = 0; i < 16; ++i) {                                          \
                p_[i] = fexp2(stv[i] - m_);                                         \
                lsum += p_[i];                                                      \
            }                                                                       \
            unsigned pk_[8];                                                        \
            _Pragma("unroll")                                                       \
            for (int i = 0; i < 8; ++i)                                             \
                asm("v_cvt_pk_bf16_f32 %0, %1, %2"                                  \
                    : "=v"(pk_[i]) : "v"(p_[2 * i]), "v"(p_[2 * i + 1]));           \
            auto rA = __builtin_amdgcn_permlane32_swap(pk_[0], pk_[2], false, false); \
            auto rB = __builtin_amdgcn_permlane32_swap(pk_[1], pk_[3], false, false); \
            auto rC = __builtin_amdgcn_permlane32_swap(pk_[4], pk_[6], false, false); \
            auto rD = __builtin_amdgcn_permlane32_swap(pk_[5], pk_[7], false, false); \
            uint32x4 f0, f1;                                                        \
            f0[0] = rA[0]; f0[1] = rB[0]; f0[2] = rA[1]; f0[3] = rB[1];             \
            f1[0] = rC[0]; f1[1] = rD[0]; f1[2] = rC[1]; f1[3] = rD[1];             \
            PF0 = __builtin_bit_cast(bf16x8, f0);                                   \
            PF1 = __builtin_bit_cast(bf16x8, f1);                                   \
        }
        TILE_P(st0, pf[0], pf[1]);
        TILE_P(st1, pf[2], pf[3]);
#undef TILE_P
        l_ += lsum;

        // ---- O^T += V^T·P^T : 8 MFMA ----
#pragma unroll
        for (int s = 0; s < 4; ++s) {
            int byo = (32 * s + 16 * hl) ^ swz;
            bf16x8 vf0 = *(const bf16x8*)((const char*)sV[cur] + ql * 128 + byo);
            bf16x8 vf1 = *(const bf16x8*)((const char*)sV[cur] + (32 + ql) * 128 + byo);
            acc0 = __builtin_amdgcn_mfma_f32_32x32x16_bf16(vf0, pf[s], acc0, 0, 0, 0);
            acc1 = __builtin_amdgcn_mfma_f32_32x32x16_bf16(vf1, pf[s], acc1, 0, 0, 0);
        }
        __syncthreads();
        cur ^= 1;
    }
#undef ATTN_STAGE

    // ---- epilogue: finalize l across halves, write O (bf16) ----
    float lf  = l_ + __shfl_xor(l_, 32, 64);
    float inv = 1.f / lf;
    const size_t rowbase = (size_t)(b * SEQ + s0 + w * 32 + ql) * DMODEL + h * 64;
#pragma unroll
    for (int reg = 0; reg < 16; ++reg) {
        int d = (reg & 3) + 8 * (reg >> 2) + 4 * hl;
        ob[rowbase + d]      = f2bf(acc0[reg] * inv);
        ob[rowbase + 32 + d] = f2bf(acc1[reg] * inv);
    }
}

// ---------------------------------------------------------------------------
#define QSCALE 0.18033688011112042f
extern "C" void kernel_launch(void* const* d_in, const int* in_sizes, int n_in,
                              void* d_out, int out_size, void* d_ws, size_t ws_size,
                              hipStream_t stream) {
    const float* x       = (const float*)d_in[0];
    const float* W_split = (const float*)d_in[1];
    const float* W_out   = (const float*)d_in[2];
    const float* Wq      = (const float*)d_in[3];
    const float* Wk      = (const float*)d_in[4];
    const float* Wv      = (const float*)d_in[5];
    float* out = (float*)d_out;

    unsigned short* xb  = (unsigned short*)d_ws;                    // 16 MB
    unsigned short* obb = xb;                                       // alias
    unsigned short* wsb = xb + (size_t)ROWS * DMODEL;               // 2 MB
    unsigned short* wob = wsb + (size_t)DMODEL * DMODEL;            // 2 MB
    unsigned short* xpb = wob + (size_t)DMODEL * DMODEL;            // 16 MB
    unsigned short* qbuf= xpb + (size_t)ROWS * DMODEL;              // 16 MB
    unsigned short* kbuf= qbuf + (size_t)ROWS * DMODEL;             // 16 MB
    unsigned short* vT  = kbuf + (size_t)ROWS * DMODEL;             // 16 MB
    unsigned short* wqb = vT + (size_t)ROWS * DMODEL;               // 128 KB
    unsigned short* wkb = wqb + (size_t)NHEAD * HD * HD;
    unsigned short* wvb = wkb + (size_t)NHEAD * HD * HD;

    dim3 blk(256);

    cvt_bf16<<<dim3(ROWS * DMODEL / 2048), blk, 0, stream>>>(x, xb, ROWS * DMODEL, 1.f);
    cvt_bf16<<<dim3(DMODEL * DMODEL / 2048), blk, 0, stream>>>(W_split, wsb, DMODEL * DMODEL, 1.f);
    cvt_bf16<<<dim3(DMODEL * DMODEL / 2048), blk, 0, stream>>>(W_out, wob, DMODEL * DMODEL, 1.f);
    cvt_bf16<<<dim3(NHEAD * HD * HD / 2048), blk, 0, stream>>>(Wq, wqb, NHEAD * HD * HD, QSCALE);
    cvt_bf16<<<dim3(NHEAD * HD * HD / 2048), blk, 0, stream>>>(Wk, wkb, NHEAD * HD * HD, 1.f);
    cvt_bf16<<<dim3(NHEAD * HD * HD / 2048), blk, 0, stream>>>(Wv, wvb, NHEAD * HD * HD, 1.f);

    gemm_bf16<true><<<dim3(DMODEL / 128, ROWS / 128), blk, 0, stream>>>(
        xb, wsb, nullptr, xpb, ROWS, DMODEL, DMODEL);
    qkv_mfma<<<dim3(NHEAD, ROWS / 128), blk, 0, stream>>>(xpb, wqb, wkb, wvb,
                                                          qbuf, kbuf, vT);
    attn_mfma<<<dim3(SEQ / 128, BATCH * NHEAD), blk, 0, stream>>>(qbuf, kbuf, vT, obb);
    gemm_bf16<false><<<dim3(DMODEL / 128, ROWS / 128), blk, 0, stream>>>(
        obb, wob, out, nullptr, ROWS, DMODEL, DMODEL);
}

// Round 7
// 131.496 us; speedup vs baseline: 10.8267x; 1.1297x over previous
//
#include <hip/hip_runtime.h>
#include <math.h>

#define NHEAD 16
#define HD 64
#define DMODEL 1024
#define SEQ 1024
#define BATCH 8
#define ROWS (BATCH * SEQ)   // 8192

typedef __attribute__((ext_vector_type(8))) short bf16x8;
typedef __attribute__((ext_vector_type(8))) short short8v;
typedef __attribute__((ext_vector_type(4))) float f32x4;
typedef __attribute__((ext_vector_type(16))) float f32x16;
typedef __attribute__((ext_vector_type(4))) short short4v;
typedef __attribute__((ext_vector_type(4))) unsigned int uint32x4;

__device__ __forceinline__ unsigned short f2bf(float f) {
    unsigned u = __builtin_bit_cast(unsigned, f);
    u += 0x7FFF + ((u >> 16) & 1);          // RNE
    return (unsigned short)(u >> 16);
}

__device__ __forceinline__ float fexp2(float x) {
#if __has_builtin(__builtin_amdgcn_exp2f)
    return __builtin_amdgcn_exp2f(x);
#else
    return __expf(x * 0.6931471805599453f);
#endif
}

__device__ __forceinline__ void gload16(const void* g, void* l) {
    __builtin_amdgcn_global_load_lds(
        (const __attribute__((address_space(1))) unsigned int*)g,
        (__attribute__((address_space(3))) unsigned int*)l, 16, 0, 0);
}

// ---------------------------------------------------------------------------
// f32 -> bf16 convert with scale (n multiple of 8)
// ---------------------------------------------------------------------------
__global__ __launch_bounds__(256) void cvt_bf16(const float* __restrict__ src,
                                                unsigned short* __restrict__ dst,
                                                int n, float scale) {
    int i = (blockIdx.x * 256 + threadIdx.x) * 8;
    if (i >= n) return;
    float4 a = *(const float4*)(src + i);
    float4 b = *(const float4*)(src + i + 4);
    short8v o;
    o[0] = (short)f2bf(a.x * scale); o[1] = (short)f2bf(a.y * scale);
    o[2] = (short)f2bf(a.z * scale); o[3] = (short)f2bf(a.w * scale);
    o[4] = (short)f2bf(b.x * scale); o[5] = (short)f2bf(b.y * scale);
    o[6] = (short)f2bf(b.z * scale); o[7] = (short)f2bf(b.w * scale);
    *(short8v*)(dst + i) = o;
}

// ---------------------------------------------------------------------------
// Fused GEMM1 + QKV: xp-tile = x @ W_split^T (128x128, covers heads 2bx,2bx+1),
// then in-LDS per-head q/k/v projections. Writes q,k (row layout) and vT.
// ---------------------------------------------------------------------------
__global__ __launch_bounds__(256) void gemm1_qkv(const unsigned short* __restrict__ A,
                                                 const unsigned short* __restrict__ B,
                                                 const unsigned short* __restrict__ wqb,
                                                 const unsigned short* __restrict__ wkb,
                                                 const unsigned short* __restrict__ wvb,
                                                 unsigned short* __restrict__ qb,
                                                 unsigned short* __restrict__ kbuf,
                                                 unsigned short* __restrict__ vT) {
    __shared__ char lds[65536];   // dbuf staging (64K) -> xp tile (32K) + weights (24K)
    const int tid  = threadIdx.x;
    const int w    = tid >> 6;
    const int lane = tid & 63;
    const int lr   = lane & 15, lg = lane >> 4;
    const int wr   = w >> 1,  wc = w & 1;
    const int m0   = blockIdx.y * 128;
    const int n0   = blockIdx.x * 128;
    const int K    = DMODEL;

    f32x4 acc[4][4] = {};

    const int srow   = lane >> 3;
    const int swbyte = ((lane & 7) ^ srow) << 4;

#define G1_STAGE(buf, k0)                                                          \
    {                                                                              \
        _Pragma("unroll")                                                          \
        for (int c = 0; c < 4; ++c) {                                              \
            int chunk = w * 4 + c;                                                 \
            int row   = chunk * 8 + srow;                                          \
            gload16((const char*)A + ((size_t)(m0 + row) * K + (k0)) * 2 + swbyte, \
                    lds + (buf) * 16384 + chunk * 1024);                           \
            gload16((const char*)B + ((size_t)(n0 + row) * K + (k0)) * 2 + swbyte, \
                    lds + 32768 + (buf) * 16384 + chunk * 1024);                   \
        }                                                                          \
    }

    G1_STAGE(0, 0);
    __syncthreads();

    int cur = 0;
    for (int t = 0; t < K / 64; ++t) {
        if (t + 1 < K / 64) G1_STAGE(cur ^ 1, (t + 1) * 64);

#pragma unroll
        for (int k2 = 0; k2 < 2; ++k2) {
            bf16x8 af[4], bg[4];
#pragma unroll
            for (int f = 0; f < 4; ++f) {
                int row = wr * 64 + f * 16 + lr;
                af[f] = *(const bf16x8*)(lds + cur * 16384 + row * 128 +
                                         ((k2 * 64 + lg * 16) ^ ((row & 7) << 4)));
            }
#pragma unroll
            for (int g = 0; g < 4; ++g) {
                int row = wc * 64 + g * 16 + lr;
                bg[g] = *(const bf16x8*)(lds + 32768 + cur * 16384 + row * 128 +
                                         ((k2 * 64 + lg * 16) ^ ((row & 7) << 4)));
            }
#pragma unroll
            for (int f = 0; f < 4; ++f)
#pragma unroll
                for (int g = 0; g < 4; ++g)
                    acc[f][g] = __builtin_amdgcn_mfma_f32_16x16x32_bf16(af[f], bg[g],
                                                                        acc[f][g], 0, 0, 0);
        }
        __syncthreads();
        cur ^= 1;
    }
#undef G1_STAGE

    // ---- epilogue: xp tile -> LDS bf16 [128 rows][256 B], swizzled ----
#pragma unroll
    for (int f = 0; f < 4; ++f)
#pragma unroll
        for (int g = 0; g < 4; ++g)
#pragma unroll
            for (int r = 0; r < 4; ++r) {
                int mrow = wr * 64 + f * 16 + lg * 4 + r;
                int ncol = wc * 64 + g * 16 + lr;
                *(unsigned short*)(lds + mrow * 256 + ((ncol * 2) ^ ((mrow & 7) << 4))) =
                    f2bf(acc[f][g][r]);
            }

    const int b  = m0 >> 10;
    const int sl = m0 & 1023;

#pragma unroll
    for (int hh = 0; hh < 2; ++hh) {
        const int h = blockIdx.x * 2 + hh;
        // stage Wq/Wk/Wv[h] into lds[32768 + p*8192) (24 chunks over 4 waves)
#pragma unroll
        for (int i = 0; i < 6; ++i) {
            int c   = w * 6 + i;                   // 0..23
            int p   = c >> 3, rc = c & 7;
            int row = rc * 8 + srow;
            const unsigned short* ws = (p == 0) ? wqb : (p == 1) ? wkb : wvb;
            gload16((const char*)ws + ((size_t)(h * 64 + row) * 64) * 2 + swbyte,
                    lds + 32768 + p * 8192 + rc * 1024);
        }
        __syncthreads();

        f32x4 a2[3][2][4] = {};
#pragma unroll
        for (int k2 = 0; k2 < 2; ++k2) {
            bf16x8 af[2];
#pragma unroll
            for (int f = 0; f < 2; ++f) {
                int row = w * 32 + f * 16 + lr;
                af[f] = *(const bf16x8*)(lds + row * 256 +
                                         ((hh * 128 + k2 * 64 + lg * 16) ^ ((row & 7) << 4)));
            }
#pragma unroll
            for (int p = 0; p < 3; ++p)
#pragma unroll
                for (int g = 0; g < 4; ++g) {
                    int o = g * 16 + lr;
                    bf16x8 bg = *(const bf16x8*)(lds + 32768 + p * 8192 + o * 128 +
                                                 ((k2 * 64 + lg * 16) ^ ((o & 7) << 4)));
#pragma unroll
                    for (int f = 0; f < 2; ++f)
                        a2[p][f][g] = __builtin_amdgcn_mfma_f32_16x16x32_bf16(af[f], bg,
                                                                              a2[p][f][g], 0, 0, 0);
                }
        }

#pragma unroll
        for (int f = 0; f < 2; ++f)
#pragma unroll
            for (int g = 0; g < 4; ++g) {
#pragma unroll
                for (int r = 0; r < 4; ++r) {
                    size_t idx = (size_t)(m0 + w * 32 + f * 16 + lg * 4 + r) * DMODEL +
                                 h * 64 + g * 16 + lr;
                    qb[idx]   = f2bf(a2[0][f][g][r]);
                    kbuf[idx] = f2bf(a2[1][f][g][r]);
                }
                short4v pv;
#pragma unroll
                for (int r = 0; r < 4; ++r) pv[r] = (short)f2bf(a2[2][f][g][r]);
                size_t o = (size_t)(b * 16 + h) * 64 + g * 16 + lr;
                *(short4v*)(vT + o * SEQ + sl + w * 32 + f * 16 + lg * 4) = pv;
            }
        __syncthreads();   // weights region re-staged next head
    }
}

// ---------------------------------------------------------------------------
// bf16 MFMA GEMM (f32 out), 2-phase pipelined — GEMM2 only.
// ---------------------------------------------------------------------------
__global__ __launch_bounds__(256) void gemm_bf16(const unsigned short* __restrict__ A,
                                                 const unsigned short* __restrict__ B,
                                                 float* __restrict__ Cf,
                                                 int M, int N, int K) {
    __shared__ char sA[2][16384];
    __shared__ char sB[2][16384];
    const int tid  = threadIdx.x;
    const int w    = tid >> 6;
    const int lane = tid & 63;
    const int lr   = lane & 15, lg = lane >> 4;
    const int wr   = w >> 1,  wc = w & 1;
    const int m0   = blockIdx.y * 128;
    const int n0   = blockIdx.x * 128;

    f32x4 acc[4][4] = {};

    const int srow   = lane >> 3;
    const int swbyte = ((lane & 7) ^ srow) << 4;
    const int nt     = K / 64;

#define GEMM_STAGE(buf, k0)                                                        \
    {                                                                              \
        _Pragma("unroll")                                                          \
        for (int c = 0; c < 4; ++c) {                                              \
            int chunk = w * 4 + c;                                                 \
            int row   = chunk * 8 + srow;                                          \
            gload16((const char*)A + ((size_t)(m0 + row) * K + (k0)) * 2 + swbyte, \
                    sA[buf] + chunk * 1024);                                       \
            gload16((const char*)B + ((size_t)(n0 + row) * K + (k0)) * 2 + swbyte, \
                    sB[buf] + chunk * 1024);                                       \
        }                                                                          \
    }

    GEMM_STAGE(0, 0);
    __syncthreads();

    int cur = 0;
    for (int t = 0; t < nt; ++t) {
        if (t + 1 < nt) GEMM_STAGE(cur ^ 1, (t + 1) * 64);

#pragma unroll
        for (int k2 = 0; k2 < 2; ++k2) {
            bf16x8 af[4], bg[4];
#pragma unroll
            for (int f = 0; f < 4; ++f) {
                int row = wr * 64 + f * 16 + lr;
                af[f] = *(const bf16x8*)(sA[cur] + row * 128 +
                                         ((k2 * 64 + lg * 16) ^ ((row & 7) << 4)));
            }
#pragma unroll
            for (int g = 0; g < 4; ++g) {
                int row = wc * 64 + g * 16 + lr;
                bg[g] = *(const bf16x8*)(sB[cur] + row * 128 +
                                         ((k2 * 64 + lg * 16) ^ ((row & 7) << 4)));
            }
#pragma unroll
            for (int f = 0; f < 4; ++f)
#pragma unroll
                for (int g = 0; g < 4; ++g)
                    acc[f][g] = __builtin_amdgcn_mfma_f32_16x16x32_bf16(af[f], bg[g],
                                                                        acc[f][g], 0, 0, 0);
        }
        __syncthreads();
        cur ^= 1;
    }
#undef GEMM_STAGE

#pragma unroll
    for (int f = 0; f < 4; ++f)
#pragma unroll
        for (int g = 0; g < 4; ++g)
#pragma unroll
            for (int r = 0; r < 4; ++r)
                Cf[(size_t)(m0 + wr * 64 + f * 16 + lg * 4 + r) * N +
                   n0 + wc * 64 + g * 16 + lr] = acc[f][g][r];
}

// ---------------------------------------------------------------------------
// MFMA flash attention v5: 8 waves x 32 q-rows (256 q/block) sharing K/V
// staging; 32x32x16 swapped-operand, in-register softmax, setprio on MFMA.
// ---------------------------------------------------------------------------
__global__ __launch_bounds__(512) void attn_mfma(const unsigned short* __restrict__ qb,
                                                 const unsigned short* __restrict__ kb,
                                                 const unsigned short* __restrict__ vT,
                                                 unsigned short* __restrict__ ob) {
    __shared__ unsigned short sK[2][4096];   // 2 x 8 KB: 64 keys x 128B (swizzled)
    __shared__ unsigned short sV[2][4096];   // 2 x 8 KB: V^T 64 d x 128B (swizzled)

    const int tid  = threadIdx.x;
    const int w    = tid >> 6;           // 0..7
    const int lane = tid & 63;
    const int ql   = lane & 31;
    const int hl   = lane >> 5;
    const int bh   = blockIdx.y;
    const int b    = bh >> 4, h = bh & 15;
    const int s0   = blockIdx.x * 256;

    const unsigned short* qrow = qb + ((size_t)(b * SEQ + s0 + w * 32 + ql) * DMODEL + h * 64);
    bf16x8 qf[4];
#pragma unroll
    for (int s = 0; s < 4; ++s)
        qf[s] = *(const bf16x8*)(qrow + 16 * s + 8 * hl);

    f32x16 acc0 = {}, acc1 = {};
    float m_ = -1e30f, l_ = 0.f;

    const int srow = lane >> 3;
    const int ssw  = ((lane & 7) << 4) ^ (srow << 4);
    const int swz  = (ql & 7) << 4;

#define ATTN_STAGE(buf, kt)                                                          \
    {                                                                                \
        int row = w * 8 + srow;                                                      \
        gload16((const char*)kb +                                                    \
                    (((size_t)(b * SEQ + (kt) * 64 + row) * DMODEL + h * 64) * 2) + ssw, \
                (char*)sK[buf] + w * 1024);                                          \
        gload16((const char*)vT +                                                    \
                    (((size_t)(bh * 64 + row) * SEQ + (kt) * 64) * 2) + ssw,         \
                (char*)sV[buf] + w * 1024);                                          \
    }

    ATTN_STAGE(0, 0);
    __syncthreads();

    int cur = 0;
    for (int kt = 0; kt < SEQ / 64; ++kt) {
        if (kt + 1 < SEQ / 64) ATTN_STAGE(cur ^ 1, kt + 1);

        // ---- S^T = K·Q^T ----
        f32x16 st0 = {}, st1 = {};
        __builtin_amdgcn_s_setprio(1);
#pragma unroll
        for (int s = 0; s < 4; ++s) {
            int byo = (32 * s + 16 * hl) ^ swz;
            bf16x8 kf0 = *(const bf16x8*)((const char*)sK[cur] + ql * 128 + byo);
            bf16x8 kf1 = *(const bf16x8*)((const char*)sK[cur] + (32 + ql) * 128 + byo);
            st0 = __builtin_amdgcn_mfma_f32_32x32x16_bf16(kf0, qf[s], st0, 0, 0, 0);
            st1 = __builtin_amdgcn_mfma_f32_32x32x16_bf16(kf1, qf[s], st1, 0, 0, 0);
        }
        __builtin_amdgcn_s_setprio(0);

        // ---- defer-max ----
        float mx = st0[0];
#pragma unroll
        for (int i = 1; i < 16; ++i) mx = fmaxf(mx, st0[i]);
#pragma unroll
        for (int i = 0; i < 16; ++i) mx = fmaxf(mx, st1[i]);
        if (__any(mx > m_ + 8.f)) {
            float rm = fmaxf(mx, __shfl_xor(mx, 32, 64));
            float mn = fmaxf(m_, rm);
            float al = fexp2(m_ - mn);
            m_ = mn;
            l_ *= al;
#pragma unroll
            for (int i = 0; i < 16; ++i) { acc0[i] *= al; acc1[i] *= al; }
        }

        // ---- P = exp2(S^T - m), pack + permlane-assemble B-frags ----
        bf16x8 pf[4];
        float lsum = 0.f;
#define TILE_P(stv, PF0, PF1)                                                       \
        {                                                                           \
            float p_[16];                                                           \
            _Pragma("unroll")                                                       \
            for (int i = 0; i < 16; ++i) {                                          \
                p_[i] = fexp2(stv[i] - m_);                                         \
                lsum += p_[i];                                                      \
            }                                                                       \
            unsigned pk_[8];                                                        \
            _Pragma("unroll")                                                       \
            for (int i = 0; i < 8; ++i)                                             \
                asm("v_cvt_pk_bf16_f32 %0, %1, %2"                                  \
                    : "=v"(pk_[i]) : "v"(p_[2 * i]), "v"(p_[2 * i + 1]));           \
            auto rA = __builtin_amdgcn_permlane32_swap(pk_[0], pk_[2], false, false); \
            auto rB = __builtin_amdgcn_permlane32_swap(pk_[1], pk_[3], false, false); \
            auto rC = __builtin_amdgcn_permlane32_swap(pk_[4], pk_[6], false, false); \
            auto rD = __builtin_amdgcn_permlane32_swap(pk_[5], pk_[7], false, false); \
            uint32x4 f0, f1;                                                        \
            f0[0] = rA[0]; f0[1] = rB[0]; f0[2] = rA[1]; f0[3] = rB[1];             \
            f1[0] = rC[0]; f1[1] = rD[0]; f1[2] = rC[1]; f1[3] = rD[1];             \
            PF0 = __builtin_bit_cast(bf16x8, f0);                                   \
            PF1 = __builtin_bit_cast(bf16x8, f1);                                   \
        }
        TILE_P(st0, pf[0], pf[1]);
        TILE_P(st1, pf[2], pf[3]);
#undef TILE_P
        l_ += lsum;

        // ---- O^T += V^T·P^T ----
        __builtin_amdgcn_s_setprio(1);
#pragma unroll
        for (int s = 0; s < 4; ++s) {
            int byo = (32 * s + 16 * hl) ^ swz;
            bf16x8 vf0 = *(const bf16x8*)((const char*)sV[cur] + ql * 128 + byo);
            bf16x8 vf1 = *(const bf16x8*)((const char*)sV[cur] + (32 + ql) * 128 + byo);
            acc0 = __builtin_amdgcn_mfma_f32_32x32x16_bf16(vf0, pf[s], acc0, 0, 0, 0);
            acc1 = __builtin_amdgcn_mfma_f32_32x32x16_bf16(vf1, pf[s], acc1, 0, 0, 0);
        }
        __builtin_amdgcn_s_setprio(0);
        __syncthreads();
        cur ^= 1;
    }
#undef ATTN_STAGE

    float lf  = l_ + __shfl_xor(l_, 32, 64);
    float inv = 1.f / lf;
    const size_t rowbase = (size_t)(b * SEQ + s0 + w * 32 + ql) * DMODEL + h * 64;
#pragma unroll
    for (int reg = 0; reg < 16; ++reg) {
        int d = (reg & 3) + 8 * (reg >> 2) + 4 * hl;
        ob[rowbase + d]      = f2bf(acc0[reg] * inv);
        ob[rowbase + 32 + d] = f2bf(acc1[reg] * inv);
    }
}

// ---------------------------------------------------------------------------
#define QSCALE 0.18033688011112042f
extern "C" void kernel_launch(void* const* d_in, const int* in_sizes, int n_in,
                              void* d_out, int out_size, void* d_ws, size_t ws_size,
                              hipStream_t stream) {
    const float* x       = (const float*)d_in[0];
    const float* W_split = (const float*)d_in[1];
    const float* W_out   = (const float*)d_in[2];
    const float* Wq      = (const float*)d_in[3];
    const float* Wk      = (const float*)d_in[4];
    const float* Wv      = (const float*)d_in[5];
    float* out = (float*)d_out;

    unsigned short* xb  = (unsigned short*)d_ws;                    // 16 MB
    unsigned short* obb = xb;                                       // alias (xb dead post-GEMM1)
    unsigned short* wsb = xb + (size_t)ROWS * DMODEL;               // 2 MB
    unsigned short* wob = wsb + (size_t)DMODEL * DMODEL;            // 2 MB
    unsigned short* qbuf= wob + (size_t)DMODEL * DMODEL;            // 16 MB
    unsigned short* kbuf= qbuf + (size_t)ROWS * DMODEL;             // 16 MB
    unsigned short* vT  = kbuf + (size_t)ROWS * DMODEL;             // 16 MB
    unsigned short* wqb = vT + (size_t)ROWS * DMODEL;               // 128 KB
    unsigned short* wkb = wqb + (size_t)NHEAD * HD * HD;
    unsigned short* wvb = wkb + (size_t)NHEAD * HD * HD;

    dim3 blk(256);

    cvt_bf16<<<dim3(ROWS * DMODEL / 2048), blk, 0, stream>>>(x, xb, ROWS * DMODEL, 1.f);
    cvt_bf16<<<dim3(DMODEL * DMODEL / 2048), blk, 0, stream>>>(W_split, wsb, DMODEL * DMODEL, 1.f);
    cvt_bf16<<<dim3(DMODEL * DMODEL / 2048), blk, 0, stream>>>(W_out, wob, DMODEL * DMODEL, 1.f);
    cvt_bf16<<<dim3(NHEAD * HD * HD / 2048), blk, 0, stream>>>(Wq, wqb, NHEAD * HD * HD, QSCALE);
    cvt_bf16<<<dim3(NHEAD * HD * HD / 2048), blk, 0, stream>>>(Wk, wkb, NHEAD * HD * HD, 1.f);
    cvt_bf16<<<dim3(NHEAD * HD * HD / 2048), blk, 0, stream>>>(Wv, wvb, NHEAD * HD * HD, 1.f);

    // 1+2) fused: xp tile in LDS, q/k/vT out
    gemm1_qkv<<<dim3(DMODEL / 128, ROWS / 128), blk, 0, stream>>>(
        xb, wsb, wqb, wkb, wvb, qbuf, kbuf, vT);
    // 3) flash attention v5 -> obb (bf16)
    attn_mfma<<<dim3(SEQ / 256, BATCH * NHEAD), dim3(512), 0, stream>>>(qbuf, kbuf, vT, obb);
    // 4) out = obb @ W_out^T (f32)
    gemm_bf16<<<dim3(DMODEL / 128, ROWS / 128), blk, 0, stream>>>(
        obb, wob, out, ROWS, DMODEL, DMODEL);
}

// Round 8
// 128.600 us; speedup vs baseline: 11.0705x; 1.0225x over previous
//
#include <hip/hip_runtime.h>
#include <math.h>

#define NHEAD 16
#define HD 64
#define DMODEL 1024
#define SEQ 1024
#define BATCH 8
#define ROWS (BATCH * SEQ)   // 8192

typedef __attribute__((ext_vector_type(8))) short bf16x8;
typedef __attribute__((ext_vector_type(8))) short short8v;
typedef __attribute__((ext_vector_type(4))) float f32x4;
typedef __attribute__((ext_vector_type(16))) float f32x16;
typedef __attribute__((ext_vector_type(4))) short short4v;
typedef __attribute__((ext_vector_type(4))) unsigned int uint32x4;

__device__ __forceinline__ unsigned short f2bf(float f) {
    unsigned u = __builtin_bit_cast(unsigned, f);
    u += 0x7FFF + ((u >> 16) & 1);          // RNE
    return (unsigned short)(u >> 16);
}

__device__ __forceinline__ float fexp2(float x) {
#if __has_builtin(__builtin_amdgcn_exp2f)
    return __builtin_amdgcn_exp2f(x);
#else
    return __expf(x * 0.6931471805599453f);
#endif
}

__device__ __forceinline__ void gload16(const void* g, void* l) {
    __builtin_amdgcn_global_load_lds(
        (const __attribute__((address_space(1))) unsigned int*)g,
        (__attribute__((address_space(3))) unsigned int*)l, 16, 0, 0);
}

// ---------------------------------------------------------------------------
// f32 -> bf16 convert with scale (n multiple of 8)
// ---------------------------------------------------------------------------
__global__ __launch_bounds__(256) void cvt_bf16(const float* __restrict__ src,
                                                unsigned short* __restrict__ dst,
                                                int n, float scale) {
    int i = (blockIdx.x * 256 + threadIdx.x) * 8;
    if (i >= n) return;
    float4 a = *(const float4*)(src + i);
    float4 b = *(const float4*)(src + i + 4);
    short8v o;
    o[0] = (short)f2bf(a.x * scale); o[1] = (short)f2bf(a.y * scale);
    o[2] = (short)f2bf(a.z * scale); o[3] = (short)f2bf(a.w * scale);
    o[4] = (short)f2bf(b.x * scale); o[5] = (short)f2bf(b.y * scale);
    o[6] = (short)f2bf(b.z * scale); o[7] = (short)f2bf(b.w * scale);
    *(short8v*)(dst + i) = o;
}

// ---------------------------------------------------------------------------
// Fused GEMM1 + QKV. Grid TRANSPOSED: blockIdx.x = m-tile (A-panel cohesion
// per XCD), blockIdx.y = n-tile (covers heads 2y, 2y+1).
// ---------------------------------------------------------------------------
__global__ __launch_bounds__(256) void gemm1_qkv(const unsigned short* __restrict__ A,
                                                 const unsigned short* __restrict__ B,
                                                 const unsigned short* __restrict__ wqb,
                                                 const unsigned short* __restrict__ wkb,
                                                 const unsigned short* __restrict__ wvb,
                                                 unsigned short* __restrict__ qb,
                                                 unsigned short* __restrict__ kbuf,
                                                 unsigned short* __restrict__ vT) {
    __shared__ char lds[65536];
    const int tid  = threadIdx.x;
    const int w    = tid >> 6;
    const int lane = tid & 63;
    const int lr   = lane & 15, lg = lane >> 4;
    const int wr   = w >> 1,  wc = w & 1;
    const int m0   = blockIdx.x * 128;     // transposed
    const int n0   = blockIdx.y * 128;
    const int K    = DMODEL;

    f32x4 acc[4][4] = {};

    const int srow   = lane >> 3;
    const int swbyte = ((lane & 7) ^ srow) << 4;

#define G1_STAGE(buf, k0)                                                          \
    {                                                                              \
        _Pragma("unroll")                                                          \
        for (int c = 0; c < 4; ++c) {                                              \
            int chunk = w * 4 + c;                                                 \
            int row   = chunk * 8 + srow;                                          \
            gload16((const char*)A + ((size_t)(m0 + row) * K + (k0)) * 2 + swbyte, \
                    lds + (buf) * 16384 + chunk * 1024);                           \
            gload16((const char*)B + ((size_t)(n0 + row) * K + (k0)) * 2 + swbyte, \
                    lds + 32768 + (buf) * 16384 + chunk * 1024);                   \
        }                                                                          \
    }

    G1_STAGE(0, 0);
    __syncthreads();

    int cur = 0;
    for (int t = 0; t < K / 64; ++t) {
        if (t + 1 < K / 64) G1_STAGE(cur ^ 1, (t + 1) * 64);

#pragma unroll
        for (int k2 = 0; k2 < 2; ++k2) {
            bf16x8 af[4], bg[4];
#pragma unroll
            for (int f = 0; f < 4; ++f) {
                int row = wr * 64 + f * 16 + lr;
                af[f] = *(const bf16x8*)(lds + cur * 16384 + row * 128 +
                                         ((k2 * 64 + lg * 16) ^ ((row & 7) << 4)));
            }
#pragma unroll
            for (int g = 0; g < 4; ++g) {
                int row = wc * 64 + g * 16 + lr;
                bg[g] = *(const bf16x8*)(lds + 32768 + cur * 16384 + row * 128 +
                                         ((k2 * 64 + lg * 16) ^ ((row & 7) << 4)));
            }
#pragma unroll
            for (int f = 0; f < 4; ++f)
#pragma unroll
                for (int g = 0; g < 4; ++g)
                    acc[f][g] = __builtin_amdgcn_mfma_f32_16x16x32_bf16(af[f], bg[g],
                                                                        acc[f][g], 0, 0, 0);
        }
        __syncthreads();
        cur ^= 1;
    }
#undef G1_STAGE

    // ---- epilogue: xp tile -> LDS bf16 [128 rows][256 B], swizzled ----
#pragma unroll
    for (int f = 0; f < 4; ++f)
#pragma unroll
        for (int g = 0; g < 4; ++g)
#pragma unroll
            for (int r = 0; r < 4; ++r) {
                int mrow = wr * 64 + f * 16 + lg * 4 + r;
                int ncol = wc * 64 + g * 16 + lr;
                *(unsigned short*)(lds + mrow * 256 + ((ncol * 2) ^ ((mrow & 7) << 4))) =
                    f2bf(acc[f][g][r]);
            }

    const int b  = m0 >> 10;
    const int sl = m0 & 1023;

#pragma unroll
    for (int hh = 0; hh < 2; ++hh) {
        const int h = blockIdx.y * 2 + hh;    // transposed
#pragma unroll
        for (int i = 0; i < 6; ++i) {
            int c   = w * 6 + i;
            int p   = c >> 3, rc = c & 7;
            int row = rc * 8 + srow;
            const unsigned short* ws = (p == 0) ? wqb : (p == 1) ? wkb : wvb;
            gload16((const char*)ws + ((size_t)(h * 64 + row) * 64) * 2 + swbyte,
                    lds + 32768 + p * 8192 + rc * 1024);
        }
        __syncthreads();

        f32x4 a2[3][2][4] = {};
#pragma unroll
        for (int k2 = 0; k2 < 2; ++k2) {
            bf16x8 af[2];
#pragma unroll
            for (int f = 0; f < 2; ++f) {
                int row = w * 32 + f * 16 + lr;
                af[f] = *(const bf16x8*)(lds + row * 256 +
                                         ((hh * 128 + k2 * 64 + lg * 16) ^ ((row & 7) << 4)));
            }
#pragma unroll
            for (int p = 0; p < 3; ++p)
#pragma unroll
                for (int g = 0; g < 4; ++g) {
                    int o = g * 16 + lr;
                    bf16x8 bg = *(const bf16x8*)(lds + 32768 + p * 8192 + o * 128 +
                                                 ((k2 * 64 + lg * 16) ^ ((o & 7) << 4)));
#pragma unroll
                    for (int f = 0; f < 2; ++f)
                        a2[p][f][g] = __builtin_amdgcn_mfma_f32_16x16x32_bf16(af[f], bg,
                                                                              a2[p][f][g], 0, 0, 0);
                }
        }

#pragma unroll
        for (int f = 0; f < 2; ++f)
#pragma unroll
            for (int g = 0; g < 4; ++g) {
#pragma unroll
                for (int r = 0; r < 4; ++r) {
                    size_t idx = (size_t)(m0 + w * 32 + f * 16 + lg * 4 + r) * DMODEL +
                                 h * 64 + g * 16 + lr;
                    qb[idx]   = f2bf(a2[0][f][g][r]);
                    kbuf[idx] = f2bf(a2[1][f][g][r]);
                }
                short4v pv;
#pragma unroll
                for (int r = 0; r < 4; ++r) pv[r] = (short)f2bf(a2[2][f][g][r]);
                size_t o = (size_t)(b * 16 + h) * 64 + g * 16 + lr;
                *(short4v*)(vT + o * SEQ + sl + w * 32 + f * 16 + lg * 4) = pv;
            }
        __syncthreads();
    }
}

// ---------------------------------------------------------------------------
// bf16 MFMA GEMM (f32 out) — GEMM2. Grid TRANSPOSED (x = m-tile).
// ---------------------------------------------------------------------------
__global__ __launch_bounds__(256) void gemm_bf16(const unsigned short* __restrict__ A,
                                                 const unsigned short* __restrict__ B,
                                                 float* __restrict__ Cf,
                                                 int M, int N, int K) {
    __shared__ char sA[2][16384];
    __shared__ char sB[2][16384];
    const int tid  = threadIdx.x;
    const int w    = tid >> 6;
    const int lane = tid & 63;
    const int lr   = lane & 15, lg = lane >> 4;
    const int wr   = w >> 1,  wc = w & 1;
    const int m0   = blockIdx.x * 128;     // transposed
    const int n0   = blockIdx.y * 128;

    f32x4 acc[4][4] = {};

    const int srow   = lane >> 3;
    const int swbyte = ((lane & 7) ^ srow) << 4;
    const int nt     = K / 64;

#define GEMM_STAGE(buf, k0)                                                        \
    {                                                                              \
        _Pragma("unroll")                                                          \
        for (int c = 0; c < 4; ++c) {                                              \
            int chunk = w * 4 + c;                                                 \
            int row   = chunk * 8 + srow;                                          \
            gload16((const char*)A + ((size_t)(m0 + row) * K + (k0)) * 2 + swbyte, \
                    sA[buf] + chunk * 1024);                                       \
            gload16((const char*)B + ((size_t)(n0 + row) * K + (k0)) * 2 + swbyte, \
                    sB[buf] + chunk * 1024);                                       \
        }                                                                          \
    }

    GEMM_STAGE(0, 0);
    __syncthreads();

    int cur = 0;
    for (int t = 0; t < nt; ++t) {
        if (t + 1 < nt) GEMM_STAGE(cur ^ 1, (t + 1) * 64);

#pragma unroll
        for (int k2 = 0; k2 < 2; ++k2) {
            bf16x8 af[4], bg[4];
#pragma unroll
            for (int f = 0; f < 4; ++f) {
                int row = wr * 64 + f * 16 + lr;
                af[f] = *(const bf16x8*)(sA[cur] + row * 128 +
                                         ((k2 * 64 + lg * 16) ^ ((row & 7) << 4)));
            }
#pragma unroll
            for (int g = 0; g < 4; ++g) {
                int row = wc * 64 + g * 16 + lr;
                bg[g] = *(const bf16x8*)(sB[cur] + row * 128 +
                                         ((k2 * 64 + lg * 16) ^ ((row & 7) << 4)));
            }
#pragma unroll
            for (int f = 0; f < 4; ++f)
#pragma unroll
                for (int g = 0; g < 4; ++g)
                    acc[f][g] = __builtin_amdgcn_mfma_f32_16x16x32_bf16(af[f], bg[g],
                                                                        acc[f][g], 0, 0, 0);
        }
        __syncthreads();
        cur ^= 1;
    }
#undef GEMM_STAGE

#pragma unroll
    for (int f = 0; f < 4; ++f)
#pragma unroll
        for (int g = 0; g < 4; ++g)
#pragma unroll
            for (int r = 0; r < 4; ++r)
                Cf[(size_t)(m0 + wr * 64 + f * 16 + lg * 4 + r) * N +
                   n0 + wc * 64 + g * 16 + lr] = acc[f][g][r];
}

// ---------------------------------------------------------------------------
// MFMA flash attention v6: 4-buffer 2-ahead prefetch with counted vmcnt +
// raw s_barrier (T4). Grid transposed: blockIdx.x = bh (K/V XCD cohesion).
// ---------------------------------------------------------------------------
__global__ __launch_bounds__(512) void attn_mfma(const unsigned short* __restrict__ qb,
                                                 const unsigned short* __restrict__ kb,
                                                 const unsigned short* __restrict__ vT,
                                                 unsigned short* __restrict__ ob) {
    __shared__ unsigned short sK[4][4096];   // 4 x 8 KB
    __shared__ unsigned short sV[4][4096];   // 4 x 8 KB

    const int tid  = threadIdx.x;
    const int w    = tid >> 6;           // 0..7
    const int lane = tid & 63;
    const int ql   = lane & 31;
    const int hl   = lane >> 5;
    const int bh   = blockIdx.x;         // transposed
    const int b    = bh >> 4, h = bh & 15;
    const int s0   = blockIdx.y * 256;
    const int NT   = SEQ / 64;           // 16

    const unsigned short* qrow = qb + ((size_t)(b * SEQ + s0 + w * 32 + ql) * DMODEL + h * 64);
    bf16x8 qf[4];
#pragma unroll
    for (int s = 0; s < 4; ++s)
        qf[s] = *(const bf16x8*)(qrow + 16 * s + 8 * hl);

    f32x16 acc0 = {}, acc1 = {};
    float m_ = -1e30f, l_ = 0.f;

    const int srow = lane >> 3;
    const int ssw  = ((lane & 7) << 4) ^ (srow << 4);
    const int swz  = (ql & 7) << 4;

#define ATTN_STAGE(buf, kt)                                                          \
    {                                                                                \
        int row = w * 8 + srow;                                                      \
        gload16((const char*)kb +                                                    \
                    (((size_t)(b * SEQ + (kt) * 64 + row) * DMODEL + h * 64) * 2) + ssw, \
                (char*)sK[buf] + w * 1024);                                          \
        gload16((const char*)vT +                                                    \
                    (((size_t)(bh * 64 + row) * SEQ + (kt) * 64) * 2) + ssw,         \
                (char*)sV[buf] + w * 1024);                                          \
    }

    // prologue: 2 tiles in flight; wait oldest (t0) done, keep t1 in flight
    ATTN_STAGE(0, 0);
    ATTN_STAGE(1, 1);
    asm volatile("s_waitcnt vmcnt(2)" ::: "memory");
    __builtin_amdgcn_s_barrier();
    __builtin_amdgcn_sched_barrier(0);

    for (int kt = 0; kt < NT; ++kt) {
        const int cb = kt & 3;
        if (kt + 2 < NT) ATTN_STAGE((kt + 2) & 3, kt + 2);

        // ---- S^T = K·Q^T ----
        f32x16 st0 = {}, st1 = {};
        __builtin_amdgcn_s_setprio(1);
#pragma unroll
        for (int s = 0; s < 4; ++s) {
            int byo = (32 * s + 16 * hl) ^ swz;
            bf16x8 kf0 = *(const bf16x8*)((const char*)sK[cb] + ql * 128 + byo);
            bf16x8 kf1 = *(const bf16x8*)((const char*)sK[cb] + (32 + ql) * 128 + byo);
            st0 = __builtin_amdgcn_mfma_f32_32x32x16_bf16(kf0, qf[s], st0, 0, 0, 0);
            st1 = __builtin_amdgcn_mfma_f32_32x32x16_bf16(kf1, qf[s], st1, 0, 0, 0);
        }
        __builtin_amdgcn_s_setprio(0);

        // ---- defer-max ----
        float mx = st0[0];
#pragma unroll
        for (int i = 1; i < 16; ++i) mx = fmaxf(mx, st0[i]);
#pragma unroll
        for (int i = 0; i < 16; ++i) mx = fmaxf(mx, st1[i]);
        if (__any(mx > m_ + 8.f)) {
            float rm = fmaxf(mx, __shfl_xor(mx, 32, 64));
            float mn = fmaxf(m_, rm);
            float al = fexp2(m_ - mn);
            m_ = mn;
            l_ *= al;
#pragma unroll
            for (int i = 0; i < 16; ++i) { acc0[i] *= al; acc1[i] *= al; }
        }

        // ---- P = exp2(S^T - m), pack + permlane-assemble B-frags ----
        bf16x8 pf[4];
        float lsum = 0.f;
#define TILE_P(stv, PF0, PF1)                                                       \
        {                                                                           \
            float p_[16];                                                           \
            _Pragma("unroll")                                                       \
            for (int i = 0; i < 16; ++i) {                                          \
                p_[i] = fexp2(stv[i] - m_);                                         \
                lsum += p_[i];                                                      \
            }                                                                       \
            unsigned pk_[8];                                                        \
            _Pragma("unroll")                                                       \
            for (int i = 0; i < 8; ++i)                                             \
                asm("v_cvt_pk_bf16_f32 %0, %1, %2"                                  \
                    : "=v"(pk_[i]) : "v"(p_[2 * i]), "v"(p_[2 * i + 1]));           \
            auto rA = __builtin_amdgcn_permlane32_swap(pk_[0], pk_[2], false, false); \
            auto rB = __builtin_amdgcn_permlane32_swap(pk_[1], pk_[3], false, false); \
            auto rC = __builtin_amdgcn_permlane32_swap(pk_[4], pk_[6], false, false); \
            auto rD = __builtin_amdgcn_permlane32_swap(pk_[5], pk_[7], false, false); \
            uint32x4 f0, f1;                                                        \
            f0[0] = rA[0]; f0[1] = rB[0]; f0[2] = rA[1]; f0[3] = rB[1];             \
            f1[0] = rC[0]; f1[1] = rD[0]; f1[2] = rC[1]; f1[3] = rD[1];             \
            PF0 = __builtin_bit_cast(bf16x8, f0);                                   \
            PF1 = __builtin_bit_cast(bf16x8, f1);                                   \
        }
        TILE_P(st0, pf[0], pf[1]);
        TILE_P(st1, pf[2], pf[3]);
#undef TILE_P
        l_ += lsum;

        // ---- O^T += V^T·P^T ----
        __builtin_amdgcn_s_setprio(1);
#pragma unroll
        for (int s = 0; s < 4; ++s) {
            int byo = (32 * s + 16 * hl) ^ swz;
            bf16x8 vf0 = *(const bf16x8*)((const char*)sV[cb] + ql * 128 + byo);
            bf16x8 vf1 = *(const bf16x8*)((const char*)sV[cb] + (32 + ql) * 128 + byo);
            acc0 = __builtin_amdgcn_mfma_f32_32x32x16_bf16(vf0, pf[s], acc0, 0, 0, 0);
            acc1 = __builtin_amdgcn_mfma_f32_32x32x16_bf16(vf1, pf[s], acc1, 0, 0, 0);
        }
        __builtin_amdgcn_s_setprio(0);

        // counted-vmcnt barrier: tile kt+1 guaranteed staged, kt+2 in flight
        if (kt + 2 < NT) { asm volatile("s_waitcnt vmcnt(2)" ::: "memory"); }
        else             { asm volatile("s_waitcnt vmcnt(0)" ::: "memory"); }
        __builtin_amdgcn_s_barrier();
        __builtin_amdgcn_sched_barrier(0);
    }
#undef ATTN_STAGE

    float lf  = l_ + __shfl_xor(l_, 32, 64);
    float inv = 1.f / lf;
    const size_t rowbase = (size_t)(b * SEQ + s0 + w * 32 + ql) * DMODEL + h * 64;
#pragma unroll
    for (int reg = 0; reg < 16; ++reg) {
        int d = (reg & 3) + 8 * (reg >> 2) + 4 * hl;
        ob[rowbase + d]      = f2bf(acc0[reg] * inv);
        ob[rowbase + 32 + d] = f2bf(acc1[reg] * inv);
    }
}

// ---------------------------------------------------------------------------
#define QSCALE 0.18033688011112042f
extern "C" void kernel_launch(void* const* d_in, const int* in_sizes, int n_in,
                              void* d_out, int out_size, void* d_ws, size_t ws_size,
                              hipStream_t stream) {
    const float* x       = (const float*)d_in[0];
    const float* W_split = (const float*)d_in[1];
    const float* W_out   = (const float*)d_in[2];
    const float* Wq      = (const float*)d_in[3];
    const float* Wk      = (const float*)d_in[4];
    const float* Wv      = (const float*)d_in[5];
    float* out = (float*)d_out;

    unsigned short* xb  = (unsigned short*)d_ws;                    // 16 MB
    unsigned short* obb = xb;                                       // alias (xb dead post-gemm1)
    unsigned short* wsb = xb + (size_t)ROWS * DMODEL;               // 2 MB
    unsigned short* wob = wsb + (size_t)DMODEL * DMODEL;            // 2 MB
    unsigned short* qbuf= wob + (size_t)DMODEL * DMODEL;            // 16 MB
    unsigned short* kbuf= qbuf + (size_t)ROWS * DMODEL;             // 16 MB
    unsigned short* vT  = kbuf + (size_t)ROWS * DMODEL;             // 16 MB
    unsigned short* wqb = vT + (size_t)ROWS * DMODEL;               // 128 KB
    unsigned short* wkb = wqb + (size_t)NHEAD * HD * HD;
    unsigned short* wvb = wkb + (size_t)NHEAD * HD * HD;

    dim3 blk(256);

    cvt_bf16<<<dim3(ROWS * DMODEL / 2048), blk, 0, stream>>>(x, xb, ROWS * DMODEL, 1.f);
    cvt_bf16<<<dim3(DMODEL * DMODEL / 2048), blk, 0, stream>>>(W_split, wsb, DMODEL * DMODEL, 1.f);
    cvt_bf16<<<dim3(DMODEL * DMODEL / 2048), blk, 0, stream>>>(W_out, wob, DMODEL * DMODEL, 1.f);
    cvt_bf16<<<dim3(NHEAD * HD * HD / 2048), blk, 0, stream>>>(Wq, wqb, NHEAD * HD * HD, QSCALE);
    cvt_bf16<<<dim3(NHEAD * HD * HD / 2048), blk, 0, stream>>>(Wk, wkb, NHEAD * HD * HD, 1.f);
    cvt_bf16<<<dim3(NHEAD * HD * HD / 2048), blk, 0, stream>>>(Wv, wvb, NHEAD * HD * HD, 1.f);

    // 1+2) fused: grid (m-tiles, n-tiles) — m fastest for A-panel XCD cohesion
    gemm1_qkv<<<dim3(ROWS / 128, DMODEL / 128), blk, 0, stream>>>(
        xb, wsb, wqb, wkb, wvb, qbuf, kbuf, vT);
    // 3) flash attention v6 — bh fastest for K/V XCD cohesion
    attn_mfma<<<dim3(BATCH * NHEAD, SEQ / 256), dim3(512), 0, stream>>>(qbuf, kbuf, vT, obb);
    // 4) out = obb @ W_out^T (f32), transposed grid
    gemm_bf16<<<dim3(ROWS / 128, DMODEL / 128), blk, 0, stream>>>(
        obb, wob, out, ROWS, DMODEL, DMODEL);
}